// Round 10
// baseline (549.691 us; speedup 1.0000x reference)
//
#include <hip/hip_runtime.h>
#include <hip/hip_bf16.h>
#include <math.h>

#define DIM 768

typedef __bf16 bf16_t;
typedef __attribute__((ext_vector_type(8))) __bf16 bf16x8;
typedef __attribute__((ext_vector_type(4))) float f32x4;

#define GLOAD_LDS16(g, l)                                                  \
    __builtin_amdgcn_global_load_lds(                                      \
        (const __attribute__((address_space(1))) void*)(g),                \
        (__attribute__((address_space(3))) void*)(l), 16, 0, 0)

__device__ __forceinline__ float bf2f(unsigned short u) {
    union { unsigned int i; float f; } x;
    x.i = ((unsigned int)u) << 16;
    return x.f;
}

// ---------------------------------------------------------------------------
// DPP-based group sum (VALU-only within 16 lanes; shfl beyond)
// ---------------------------------------------------------------------------
template <int CTRL>
__device__ __forceinline__ float dpp_add(float v) {
    int s = __builtin_amdgcn_update_dpp(0, __float_as_int(v), CTRL, 0xF, 0xF, true);
    return v + __int_as_float(s);
}

template <int G>
__device__ __forceinline__ float group_sum(float t) {
    t = dpp_add<0xB1>(t);                         // quad_perm xor1
    t = dpp_add<0x4E>(t);                         // quad_perm xor2
    t = dpp_add<0x141>(t);                        // row_half_mirror: 8-group
    if constexpr (G >= 16) t = dpp_add<0x140>(t); // row_mirror: 16-group
    if constexpr (G >= 32) t += __shfl_xor(t, 16, 64);
    if constexpr (G >= 64) t += __shfl_xor(t, 32, 64);
    return t;
}

// ---------------------------------------------------------------------------
// CSR build
// ---------------------------------------------------------------------------
__global__ __launch_bounds__(256) void hist_kernel(const int* __restrict__ dst,
                                                   int* __restrict__ deg, int E) {
    int e = blockIdx.x * 256 + threadIdx.x;
    if (e < E) atomicAdd(&deg[dst[e]], 1);
}

__global__ __launch_bounds__(1024) void scan_kernel(const int* __restrict__ deg,
                                                    int* __restrict__ row_start,
                                                    int* __restrict__ cursor, int n) {
    __shared__ int sh[1024];
    __shared__ int carry_sh;
    int tid = threadIdx.x;
    if (tid == 0) carry_sh = 0;
    __syncthreads();
    for (int base = 0; base < n; base += 1024) {
        int i = base + tid;
        int v = (i < n) ? deg[i] : 0;
        sh[tid] = v;
        __syncthreads();
        for (int off = 1; off < 1024; off <<= 1) {
            int t = (tid >= off) ? sh[tid - off] : 0;
            __syncthreads();
            sh[tid] += t;
            __syncthreads();
        }
        int incl = sh[tid];
        int carry = carry_sh;
        int excl = carry + incl - v;
        if (i < n) { row_start[i] = excl; cursor[i] = excl; }
        __syncthreads();
        if (tid == 1023) carry_sh = carry + incl;
        __syncthreads();
    }
    if (tid == 0) row_start[n] = carry_sh;
}

__global__ __launch_bounds__(256) void scatter_kernel(const int* __restrict__ src,
                                                      const int* __restrict__ dst,
                                                      int* __restrict__ cursor,
                                                      int* __restrict__ csr_src, int E) {
    int e = blockIdx.x * 256 + threadIdx.x;
    if (e < E) {
        int p = atomicAdd(&cursor[dst[e]], 1);
        csr_src[p] = src[e];
    }
}

// ---------------------------------------------------------------------------
// Degree-descending node order (LPT scheduling): 64-bin counting sort
// ---------------------------------------------------------------------------
__global__ __launch_bounds__(256) void deg_hist_kernel(const int* __restrict__ deg,
                                                       int* __restrict__ dhist, int n) {
    int i = blockIdx.x * 256 + threadIdx.x;
    if (i < n) {
        int d = deg[i]; d = d > 63 ? 63 : d;
        atomicAdd(&dhist[d], 1);
    }
}

__global__ void deg_offset_kernel(const int* __restrict__ dhist,
                                  int* __restrict__ dcur) {
    if (threadIdx.x == 0) {
        int acc = 0;
        for (int b = 63; b >= 0; --b) { dcur[b] = acc; acc += dhist[b]; }
    }
}

__global__ __launch_bounds__(256) void deg_scatter_kernel(const int* __restrict__ deg,
                                                          int* __restrict__ dcur,
                                                          int* __restrict__ order, int n) {
    int i = blockIdx.x * 256 + threadIdx.x;
    if (i < n) {
        int d = deg[i]; d = d > 63 ? 63 : d;
        int p = atomicAdd(&dcur[d], 1);
        order[p] = i;
    }
}

// ---------------------------------------------------------------------------
// fp32 -> bf16 elementwise convert (8 elems/thread)
// ---------------------------------------------------------------------------
__global__ __launch_bounds__(256) void conv_bf16_kernel(const float* __restrict__ in,
                                                        __hip_bfloat16* __restrict__ out,
                                                        int n8) {
    int i = blockIdx.x * 256 + threadIdx.x;
    if (i >= n8) return;
    const float4* p = reinterpret_cast<const float4*>(in + (size_t)i * 8);
    float4 a = p[0], b = p[1];
    __hip_bfloat16 v[8];
    v[0] = __float2bfloat16(a.x); v[1] = __float2bfloat16(a.y);
    v[2] = __float2bfloat16(a.z); v[3] = __float2bfloat16(a.w);
    v[4] = __float2bfloat16(b.x); v[5] = __float2bfloat16(b.y);
    v[6] = __float2bfloat16(b.z); v[7] = __float2bfloat16(b.w);
    *reinterpret_cast<uint4*>(out + (size_t)i * 8) = *reinterpret_cast<uint4*>(v);
}

// ---------------------------------------------------------------------------
// W [K][Nc] f32  ->  Wt [Nc][K] bf16  (tiled transpose)
// ---------------------------------------------------------------------------
__global__ __launch_bounds__(256) void transpose_bf16_kernel(const float* __restrict__ W,
                                                             __hip_bfloat16* __restrict__ Wt,
                                                             int K, int Nc) {
    __shared__ float tile[32][33];
    int bk = blockIdx.x * 32, bn = blockIdx.y * 32;
    int tx = threadIdx.x & 31, ty = threadIdx.x >> 5;  // 32 x 8
#pragma unroll
    for (int r = ty; r < 32; r += 8)
        tile[r][tx] = W[(size_t)(bk + r) * Nc + bn + tx];
    __syncthreads();
#pragma unroll
    for (int r = ty; r < 32; r += 8)
        Wt[(size_t)(bn + r) * K + bk + tx] = __float2bfloat16(tile[tx][r]);
}

// ---------------------------------------------------------------------------
// Dual bf16 MFMA GEMM, 1D grid with bijective XCD-chunk swizzle (T1/m204)
// ---------------------------------------------------------------------------
__global__ __launch_bounds__(256) void gemm_mfma_dual_kernel(
    const bf16_t* __restrict__ Xb,   // [M][768]
    const bf16_t* __restrict__ Wt,   // [1536][768]
    const float* __restrict__ b1, const float* __restrict__ b2,
    __hip_bfloat16* __restrict__ C1, __hip_bfloat16* __restrict__ C2, int M) {
    __shared__ __align__(16) bf16_t As[128 * 64];
    __shared__ __align__(16) bf16_t Bs[128 * 64];

    const int nwg = gridDim.x;
    const int o = blockIdx.x;
    const int q = nwg >> 3, r = nwg & 7;
    const int xcd = o & 7, jj = o >> 3;
    const int lin = (xcd < r ? xcd * (q + 1) : r * (q + 1) + (xcd - r) * q) + jj;
    const int bn = (lin % 12) * 128;
    const int bm = (lin / 12) * 128;

    const int tid = threadIdx.x;
    const int lane = tid & 63;
    const int w = tid >> 6;
    const int wr = w >> 1, wc = w & 1;

    f32x4 acc[4][4];
    {
        const float* bp = (bn < DIM) ? b1 : b2;
        int cb = (bn < DIM) ? bn : bn - DIM;
#pragma unroll
        for (int ni = 0; ni < 4; ++ni) {
            float bv = bp[cb + wc * 64 + ni * 16 + (lane & 15)];
#pragma unroll
            for (int mi = 0; mi < 4; ++mi) acc[mi][ni] = f32x4{bv, bv, bv, bv};
        }
    }

    const int srow = w * 32 + (lane >> 3);
    const int scol = (lane & 7) * 8;

    for (int k0 = 0; k0 < DIM; k0 += 64) {
#pragma unroll
        for (int i = 0; i < 4; ++i) {
            int rr = srow + i * 8;
            int col = scol ^ ((rr & 7) << 3);
            int rg = bm + rr; rg = rg < M ? rg : M - 1;
            GLOAD_LDS16(Xb + (size_t)rg * DIM + k0 + col, &As[(w * 32 + i * 8) * 64]);
        }
#pragma unroll
        for (int i = 0; i < 4; ++i) {
            int rr = srow + i * 8;
            int col = scol ^ ((rr & 7) << 3);
            GLOAD_LDS16(Wt + (size_t)(bn + rr) * DIM + k0 + col, &Bs[(w * 32 + i * 8) * 64]);
        }
        __syncthreads();

#pragma unroll
        for (int kk = 0; kk < 2; ++kk) {
            bf16x8 af[4], bfr[4];
            int ke = kk * 32 + (lane >> 4) * 8;
#pragma unroll
            for (int mi = 0; mi < 4; ++mi) {
                int rr = wr * 64 + mi * 16 + (lane & 15);
                af[mi] = *(const bf16x8*)&As[rr * 64 + (ke ^ ((rr & 7) << 3))];
            }
#pragma unroll
            for (int ni = 0; ni < 4; ++ni) {
                int rr = wc * 64 + ni * 16 + (lane & 15);
                bfr[ni] = *(const bf16x8*)&Bs[rr * 64 + (ke ^ ((rr & 7) << 3))];
            }
#pragma unroll
            for (int mi = 0; mi < 4; ++mi)
#pragma unroll
                for (int ni = 0; ni < 4; ++ni)
                    acc[mi][ni] = __builtin_amdgcn_mfma_f32_16x16x32_bf16(
                        af[mi], bfr[ni], acc[mi][ni], 0, 0, 0);
        }
        __syncthreads();
    }

    __hip_bfloat16* C = (bn < DIM) ? C1 : C2;
    int cb = (bn < DIM) ? bn : bn - DIM;
#pragma unroll
    for (int mi = 0; mi < 4; ++mi) {
#pragma unroll
        for (int j = 0; j < 4; ++j) {
            int row = bm + wr * 64 + mi * 16 + (lane >> 4) * 4 + j;
            if (row < M) {
#pragma unroll
                for (int ni = 0; ni < 4; ++ni) {
                    int col = cb + wc * 64 + ni * 16 + (lane & 15);
                    C[(size_t)row * DIM + col] = __float2bfloat16(acc[mi][ni][j]);
                }
            }
        }
    }
}

// ---------------------------------------------------------------------------
// Per-node GAT: round-6 structure (one wave per node, 2-deep prefetch,
// max-free softmax, DPP reduce, exp2) + LPT node order (degree-descending).
// ---------------------------------------------------------------------------
__device__ __forceinline__ void load12(const unsigned short* __restrict__ p, float* v) {
    ushort4 a = *reinterpret_cast<const ushort4*>(p);
    ushort4 b = *reinterpret_cast<const ushort4*>(p + 4);
    ushort4 c = *reinterpret_cast<const ushort4*>(p + 8);
    v[0] = bf2f(a.x); v[1] = bf2f(a.y); v[2] = bf2f(a.z); v[3] = bf2f(a.w);
    v[4] = bf2f(b.x); v[5] = bf2f(b.y); v[6] = bf2f(b.z); v[7] = bf2f(b.w);
    v[8] = bf2f(c.x); v[9] = bf2f(c.y); v[10] = bf2f(c.z); v[11] = bf2f(c.w);
}

// one edge: logit -> DPP group reduce -> exp2 (log2e pre-folded into av)
#define PROCESS(FV)                                                         \
    do {                                                                    \
        float t = 0.f;                                                      \
        _Pragma("unroll") for (int j = 0; j < 12; ++j) {                    \
            float u = FV[j] + fdv[j];                                       \
            u = fmaxf(u, 0.2f * u);                                         \
            t = fmaf(u, av[j], t);                                          \
        }                                                                   \
        t = group_sum<G>(t);                                                \
        float ex = exp2f(t);                                                \
        denom += ex;                                                        \
        _Pragma("unroll") for (int j = 0; j < 12; ++j)                      \
            agg[j] = fmaf(ex, FV[j], agg[j]);                               \
    } while (0)

template <int H>
__global__ __launch_bounds__(256) void gat_node_kernel(
    const unsigned short* __restrict__ fs, const unsigned short* __restrict__ fd,
    const int* __restrict__ row_start, const int* __restrict__ csr_src,
    const int* __restrict__ order,
    const float* __restrict__ attn, const float* __restrict__ resid,
    const float* __restrict__ ln_w, const float* __restrict__ ln_b,
    float* __restrict__ outf, __hip_bfloat16* __restrict__ outb, int n_nodes) {
    constexpr int G = 64 / H;
    int wave = threadIdx.x >> 6;
    int lane = threadIdx.x & 63;
    int idx = blockIdx.x * 4 + wave;
    if (idx >= n_nodes) return;
    int node = order[idx];
    int d0 = lane * 12;

    float fdv[12], av[12], agg[12];
    load12(fd + (size_t)node * DIM + d0, fdv);
    {
        const float* ap = attn + d0;
        const float LOG2E = 1.44269504f;  // exp(t) == exp2(t*log2e)
#pragma unroll
        for (int j = 0; j < 12; ++j) av[j] = ap[j] * LOG2E;
    }
#pragma unroll
    for (int j = 0; j < 12; ++j) agg[j] = 0.f;

    int p0 = row_start[node], p1 = row_start[node + 1];
    int np = p1 - p0;
    float denom = 0.f;

    const unsigned short* fsl = fs + d0;
    const int* ip = csr_src + p0;

    float fvA[12], fvB[12];
    if (np > 0) load12(fsl + (size_t)ip[0] * DIM, fvA);
    if (np > 1) load12(fsl + (size_t)ip[1] * DIM, fvB);

    int i = 0;
    for (; i + 2 <= np; i += 2) {
        PROCESS(fvA);
        if (i + 2 < np) load12(fsl + (size_t)ip[i + 2] * DIM, fvA);
        PROCESS(fvB);
        if (i + 3 < np) load12(fsl + (size_t)ip[i + 3] * DIM, fvB);
    }
    if (i < np) PROCESS(fvA);

    float inv = (denom > 0.f) ? 1.0f / denom : 0.f;
    float vals[12];
#pragma unroll
    for (int j = 0; j < 12; ++j) {
        float v = agg[j] * inv;
        vals[j] = (v > 0.f) ? v : expm1f(v);
    }
    if (resid != nullptr) {
        const float4* p = reinterpret_cast<const float4*>(resid + (size_t)node * DIM + d0);
        float4 q0 = p[0], q1 = p[1], q2 = p[2];
        vals[0] += q0.x; vals[1] += q0.y; vals[2] += q0.z; vals[3] += q0.w;
        vals[4] += q1.x; vals[5] += q1.y; vals[6] += q1.z; vals[7] += q1.w;
        vals[8] += q2.x; vals[9] += q2.y; vals[10] += q2.z; vals[11] += q2.w;
    }
    float s1 = 0.f;
#pragma unroll
    for (int j = 0; j < 12; ++j) s1 += vals[j];
    s1 = group_sum<64>(s1);
    float mu = s1 * (1.0f / DIM);
    float s2 = 0.f;
#pragma unroll
    for (int j = 0; j < 12; ++j) {
        float dlt = vals[j] - mu;
        s2 = fmaf(dlt, dlt, s2);
    }
    s2 = group_sum<64>(s2);
    float rs = rsqrtf(s2 * (1.0f / DIM) + 1e-5f);

    float wv[12], bv[12];
    {
        const float4* p = reinterpret_cast<const float4*>(ln_w + d0);
        float4 q0 = p[0], q1 = p[1], q2 = p[2];
        wv[0] = q0.x; wv[1] = q0.y; wv[2] = q0.z; wv[3] = q0.w;
        wv[4] = q1.x; wv[5] = q1.y; wv[6] = q1.z; wv[7] = q1.w;
        wv[8] = q2.x; wv[9] = q2.y; wv[10] = q2.z; wv[11] = q2.w;
        const float4* pb = reinterpret_cast<const float4*>(ln_b + d0);
        float4 r0 = pb[0], r1 = pb[1], r2 = pb[2];
        bv[0] = r0.x; bv[1] = r0.y; bv[2] = r0.z; bv[3] = r0.w;
        bv[4] = r1.x; bv[5] = r1.y; bv[6] = r1.z; bv[7] = r1.w;
        bv[8] = r2.x; bv[9] = r2.y; bv[10] = r2.z; bv[11] = r2.w;
    }
    float o[12];
#pragma unroll
    for (int j = 0; j < 12; ++j)
        o[j] = (vals[j] - mu) * rs * wv[j] + bv[j];

    if (outf != nullptr) {
        float* op = outf + (size_t)node * DIM + d0;
#pragma unroll
        for (int qq = 0; qq < 3; ++qq) {
            float4 t4 = make_float4(o[qq * 4 + 0], o[qq * 4 + 1], o[qq * 4 + 2], o[qq * 4 + 3]);
            *reinterpret_cast<float4*>(op + qq * 4) = t4;
        }
    }
    if (outb != nullptr) {
        __hip_bfloat16 hb[12];
#pragma unroll
        for (int j = 0; j < 12; ++j) hb[j] = __float2bfloat16(o[j]);
        unsigned short* op = (unsigned short*)outb + (size_t)node * DIM + d0;
#pragma unroll
        for (int qq = 0; qq < 3; ++qq)
            *reinterpret_cast<ushort4*>(op + qq * 4) =
                *reinterpret_cast<ushort4*>(&hb[qq * 4]);
    }
}

// ---------------------------------------------------------------------------
extern "C" void kernel_launch(void* const* d_in, const int* in_sizes, int n_in,
                              void* d_out, int out_size, void* d_ws, size_t ws_size,
                              hipStream_t stream) {
    const float* x     = (const float*)d_in[0];
    const int*   src   = (const int*)d_in[1];
    const int*   dst   = (const int*)d_in[2];
    const float* W1s   = (const float*)d_in[3];
    const float* b1s   = (const float*)d_in[4];
    const float* W1d   = (const float*)d_in[5];
    const float* b1d   = (const float*)d_in[6];
    const float* attn1 = (const float*)d_in[7];
    const float* ln1w  = (const float*)d_in[8];
    const float* ln1b  = (const float*)d_in[9];
    const float* Wos   = (const float*)d_in[10];
    const float* bos   = (const float*)d_in[11];
    const float* Wod   = (const float*)d_in[12];
    const float* bod   = (const float*)d_in[13];
    const float* attno = (const float*)d_in[14];
    const float* lnow  = (const float*)d_in[15];
    const float* lnob  = (const float*)d_in[16];
    float* out = (float*)d_out;

    const int N = in_sizes[0] / DIM;   // 20000
    const int E = in_sizes[1];         // 320000

    __hip_bfloat16* fsb = (__hip_bfloat16*)d_ws;
    __hip_bfloat16* fdb = fsb + (size_t)N * DIM;
    __hip_bfloat16* Xb  = fdb + (size_t)N * DIM;
    __hip_bfloat16* W1t = Xb + (size_t)N * DIM;
    __hip_bfloat16* Wot = W1t + (size_t)2 * DIM * DIM;
    int* csr_src   = (int*)(Wot + (size_t)2 * DIM * DIM);
    int* row_start = csr_src + E;
    int* cursor    = row_start + (N + 1);
    int* deg       = cursor + N;        // memset to 0 (with dhist below)
    int* dhist     = deg + N;           // 64
    int* dcur      = dhist + 64;        // 64
    int* order     = dcur + 64;         // N

    // --- CSR by dst + degree-descending order (shared by both layers)
    hipMemsetAsync(deg, 0, (size_t)(N + 64) * sizeof(int), stream);  // deg + dhist
    hist_kernel<<<(E + 255) / 256, 256, 0, stream>>>(dst, deg, E);
    scan_kernel<<<1, 1024, 0, stream>>>(deg, row_start, cursor, N);
    scatter_kernel<<<(E + 255) / 256, 256, 0, stream>>>(src, dst, cursor, csr_src, E);
    deg_hist_kernel<<<(N + 255) / 256, 256, 0, stream>>>(deg, dhist, N);
    deg_offset_kernel<<<1, 64, 0, stream>>>(dhist, dcur);
    deg_scatter_kernel<<<(N + 255) / 256, 256, 0, stream>>>(deg, dcur, order, N);

    // --- weight transposes (f32 -> bf16, [K][N] -> [N][K])
    dim3 tg(DIM / 32, DIM / 32);
    transpose_bf16_kernel<<<tg, 256, 0, stream>>>(W1s, W1t, DIM, DIM);
    transpose_bf16_kernel<<<tg, 256, 0, stream>>>(W1d, W1t + (size_t)DIM * DIM, DIM, DIM);
    transpose_bf16_kernel<<<tg, 256, 0, stream>>>(Wos, Wot, DIM, DIM);
    transpose_bf16_kernel<<<tg, 256, 0, stream>>>(Wod, Wot + (size_t)DIM * DIM, DIM, DIM);

    const int n8 = N * DIM / 8;
    const int mt = (N + 127) / 128;
    const int nwg = mt * 12;  // 1D swizzled grid

    // --- layer 1: GEMM -> gat (writes bf16 h straight into Xb for layer 2)
    conv_bf16_kernel<<<(n8 + 255) / 256, 256, 0, stream>>>(x, Xb, n8);
    gemm_mfma_dual_kernel<<<nwg, 256, 0, stream>>>(
        (const bf16_t*)Xb, (const bf16_t*)W1t, b1s, b1d, fsb, fdb, N);
    gat_node_kernel<8><<<(N + 3) / 4, 256, 0, stream>>>(
        (const unsigned short*)fsb, (const unsigned short*)fdb, row_start, csr_src,
        order, attn1, x, ln1w, ln1b, nullptr, Xb, N);

    // --- layer 2: GEMM -> gat -> final f32 out
    gemm_mfma_dual_kernel<<<nwg, 256, 0, stream>>>(
        (const bf16_t*)Xb, (const bf16_t*)Wot, bos, bod, fsb, fdb, N);
    gat_node_kernel<1><<<(N + 3) / 4, 256, 0, stream>>>(
        (const unsigned short*)fsb, (const unsigned short*)fdb, row_start, csr_src,
        order, attno, nullptr, lnow, lnob, out, nullptr, N);
}

// Round 11
// 462.564 us; speedup vs baseline: 1.1884x; 1.1884x over previous
//
#include <hip/hip_runtime.h>
#include <hip/hip_bf16.h>
#include <math.h>

#define DIM 768

typedef __bf16 bf16_t;
typedef __attribute__((ext_vector_type(8))) __bf16 bf16x8;
typedef __attribute__((ext_vector_type(4))) float f32x4;

#define GLOAD_LDS16(g, l)                                                  \
    __builtin_amdgcn_global_load_lds(                                      \
        (const __attribute__((address_space(1))) void*)(g),                \
        (__attribute__((address_space(3))) void*)(l), 16, 0, 0)

__device__ __forceinline__ void unpack2(unsigned int u, float& lo, float& hi) {
    lo = __uint_as_float(u << 16);
    hi = __uint_as_float(u & 0xffff0000u);
}

// ---------------------------------------------------------------------------
// DPP-based group sum (VALU-only within 16 lanes; shfl beyond)
// ---------------------------------------------------------------------------
template <int CTRL>
__device__ __forceinline__ float dpp_add(float v) {
    int s = __builtin_amdgcn_update_dpp(0, __float_as_int(v), CTRL, 0xF, 0xF, true);
    return v + __int_as_float(s);
}

template <int G>
__device__ __forceinline__ float group_sum(float t) {
    t = dpp_add<0xB1>(t);                         // quad_perm xor1
    t = dpp_add<0x4E>(t);                         // quad_perm xor2
    t = dpp_add<0x141>(t);                        // row_half_mirror: 8-group
    if constexpr (G >= 16) t = dpp_add<0x140>(t); // row_mirror: 16-group
    if constexpr (G >= 32) t += __shfl_xor(t, 16, 64);
    if constexpr (G >= 64) t += __shfl_xor(t, 32, 64);
    return t;
}

// ---------------------------------------------------------------------------
// CSR build
// ---------------------------------------------------------------------------
__global__ __launch_bounds__(256) void hist_kernel(const int* __restrict__ dst,
                                                   int* __restrict__ deg, int E) {
    int e = blockIdx.x * 256 + threadIdx.x;
    if (e < E) atomicAdd(&deg[dst[e]], 1);
}

__global__ __launch_bounds__(1024) void scan_kernel(const int* __restrict__ deg,
                                                    int* __restrict__ row_start,
                                                    int* __restrict__ cursor, int n) {
    __shared__ int sh[1024];
    __shared__ int carry_sh;
    int tid = threadIdx.x;
    if (tid == 0) carry_sh = 0;
    __syncthreads();
    for (int base = 0; base < n; base += 1024) {
        int i = base + tid;
        int v = (i < n) ? deg[i] : 0;
        sh[tid] = v;
        __syncthreads();
        for (int off = 1; off < 1024; off <<= 1) {
            int t = (tid >= off) ? sh[tid - off] : 0;
            __syncthreads();
            sh[tid] += t;
            __syncthreads();
        }
        int incl = sh[tid];
        int carry = carry_sh;
        int excl = carry + incl - v;
        if (i < n) { row_start[i] = excl; cursor[i] = excl; }
        __syncthreads();
        if (tid == 1023) carry_sh = carry + incl;
        __syncthreads();
    }
    if (tid == 0) row_start[n] = carry_sh;
}

__global__ __launch_bounds__(256) void scatter_kernel(const int* __restrict__ src,
                                                      const int* __restrict__ dst,
                                                      int* __restrict__ cursor,
                                                      int* __restrict__ csr_src, int E) {
    int e = blockIdx.x * 256 + threadIdx.x;
    if (e < E) {
        int p = atomicAdd(&cursor[dst[e]], 1);
        csr_src[p] = src[e];
    }
}

// ---------------------------------------------------------------------------
// fp32 -> bf16 elementwise convert (8 elems/thread)
// ---------------------------------------------------------------------------
__global__ __launch_bounds__(256) void conv_bf16_kernel(const float* __restrict__ in,
                                                        __hip_bfloat16* __restrict__ out,
                                                        int n8) {
    int i = blockIdx.x * 256 + threadIdx.x;
    if (i >= n8) return;
    const float4* p = reinterpret_cast<const float4*>(in + (size_t)i * 8);
    float4 a = p[0], b = p[1];
    __hip_bfloat16 v[8];
    v[0] = __float2bfloat16(a.x); v[1] = __float2bfloat16(a.y);
    v[2] = __float2bfloat16(a.z); v[3] = __float2bfloat16(a.w);
    v[4] = __float2bfloat16(b.x); v[5] = __float2bfloat16(b.y);
    v[6] = __float2bfloat16(b.z); v[7] = __float2bfloat16(b.w);
    *reinterpret_cast<uint4*>(out + (size_t)i * 8) = *reinterpret_cast<uint4*>(v);
}

// ---------------------------------------------------------------------------
// W [K][Nc] f32  ->  Wt [Nc][K] bf16  (tiled transpose)
// ---------------------------------------------------------------------------
__global__ __launch_bounds__(256) void transpose_bf16_kernel(const float* __restrict__ W,
                                                             __hip_bfloat16* __restrict__ Wt,
                                                             int K, int Nc) {
    __shared__ float tile[32][33];
    int bk = blockIdx.x * 32, bn = blockIdx.y * 32;
    int tx = threadIdx.x & 31, ty = threadIdx.x >> 5;  // 32 x 8
#pragma unroll
    for (int r = ty; r < 32; r += 8)
        tile[r][tx] = W[(size_t)(bk + r) * Nc + bn + tx];
    __syncthreads();
#pragma unroll
    for (int r = ty; r < 32; r += 8)
        Wt[(size_t)(bn + r) * K + bk + tx] = __float2bfloat16(tile[tx][r]);
}

// ---------------------------------------------------------------------------
// Dual bf16 MFMA GEMM, 1D grid with bijective XCD-chunk swizzle (T1/m204)
// ---------------------------------------------------------------------------
__global__ __launch_bounds__(256) void gemm_mfma_dual_kernel(
    const bf16_t* __restrict__ Xb,   // [M][768]
    const bf16_t* __restrict__ Wt,   // [1536][768]
    const float* __restrict__ b1, const float* __restrict__ b2,
    __hip_bfloat16* __restrict__ C1, __hip_bfloat16* __restrict__ C2, int M) {
    __shared__ __align__(16) bf16_t As[128 * 64];
    __shared__ __align__(16) bf16_t Bs[128 * 64];

    const int nwg = gridDim.x;
    const int o = blockIdx.x;
    const int q = nwg >> 3, r = nwg & 7;
    const int xcd = o & 7, jj = o >> 3;
    const int lin = (xcd < r ? xcd * (q + 1) : r * (q + 1) + (xcd - r) * q) + jj;
    const int bn = (lin % 12) * 128;
    const int bm = (lin / 12) * 128;

    const int tid = threadIdx.x;
    const int lane = tid & 63;
    const int w = tid >> 6;
    const int wr = w >> 1, wc = w & 1;

    f32x4 acc[4][4];
    {
        const float* bp = (bn < DIM) ? b1 : b2;
        int cb = (bn < DIM) ? bn : bn - DIM;
#pragma unroll
        for (int ni = 0; ni < 4; ++ni) {
            float bv = bp[cb + wc * 64 + ni * 16 + (lane & 15)];
#pragma unroll
            for (int mi = 0; mi < 4; ++mi) acc[mi][ni] = f32x4{bv, bv, bv, bv};
        }
    }

    const int srow = w * 32 + (lane >> 3);
    const int scol = (lane & 7) * 8;

    for (int k0 = 0; k0 < DIM; k0 += 64) {
#pragma unroll
        for (int i = 0; i < 4; ++i) {
            int rr = srow + i * 8;
            int col = scol ^ ((rr & 7) << 3);
            int rg = bm + rr; rg = rg < M ? rg : M - 1;
            GLOAD_LDS16(Xb + (size_t)rg * DIM + k0 + col, &As[(w * 32 + i * 8) * 64]);
        }
#pragma unroll
        for (int i = 0; i < 4; ++i) {
            int rr = srow + i * 8;
            int col = scol ^ ((rr & 7) << 3);
            GLOAD_LDS16(Wt + (size_t)(bn + rr) * DIM + k0 + col, &Bs[(w * 32 + i * 8) * 64]);
        }
        __syncthreads();

#pragma unroll
        for (int kk = 0; kk < 2; ++kk) {
            bf16x8 af[4], bfr[4];
            int ke = kk * 32 + (lane >> 4) * 8;
#pragma unroll
            for (int mi = 0; mi < 4; ++mi) {
                int rr = wr * 64 + mi * 16 + (lane & 15);
                af[mi] = *(const bf16x8*)&As[rr * 64 + (ke ^ ((rr & 7) << 3))];
            }
#pragma unroll
            for (int ni = 0; ni < 4; ++ni) {
                int rr = wc * 64 + ni * 16 + (lane & 15);
                bfr[ni] = *(const bf16x8*)&Bs[rr * 64 + (ke ^ ((rr & 7) << 3))];
            }
#pragma unroll
            for (int mi = 0; mi < 4; ++mi)
#pragma unroll
                for (int ni = 0; ni < 4; ++ni)
                    acc[mi][ni] = __builtin_amdgcn_mfma_f32_16x16x32_bf16(
                        af[mi], bfr[ni], acc[mi][ni], 0, 0, 0);
        }
        __syncthreads();
    }

    __hip_bfloat16* C = (bn < DIM) ? C1 : C2;
    int cb = (bn < DIM) ? bn : bn - DIM;
#pragma unroll
    for (int mi = 0; mi < 4; ++mi) {
#pragma unroll
        for (int j = 0; j < 4; ++j) {
            int row = bm + wr * 64 + mi * 16 + (lane >> 4) * 4 + j;
            if (row < M) {
#pragma unroll
                for (int ni = 0; ni < 4; ++ni) {
                    int col = cb + wc * 64 + ni * 16 + (lane & 15);
                    C[(size_t)row * DIM + col] = __float2bfloat16(acc[mi][ni][j]);
                }
            }
        }
    }
}

// ---------------------------------------------------------------------------
// Per-node GAT with DENSE lane mapping: lane l=8h+j owns dims
//   {96h+8j .. +7}  (one 16B bf16 load)  and  {96h+64+4j .. +3} (one 8B load).
// Every load instruction covers whole cache lines -> 24 line-requests/edge
// (vs 72 for the old stride-24 layout). Head h == lanes 8h..8h+7, so the
// 8-lane DPP reduce is unchanged; 64-lane LN sums are mapping-invariant.
// Round-6 loop structure otherwise (2-deep prefetch, max-free softmax, exp2).
// ---------------------------------------------------------------------------
__device__ __forceinline__ void load12d(const unsigned short* __restrict__ row,
                                        int offA, int offB, float* v) {
    uint4 a = *reinterpret_cast<const uint4*>(row + offA);   // 8 bf16, 16B
    uint2 b = *reinterpret_cast<const uint2*>(row + offB);   // 4 bf16, 8B
    unpack2(a.x, v[0], v[1]);
    unpack2(a.y, v[2], v[3]);
    unpack2(a.z, v[4], v[5]);
    unpack2(a.w, v[6], v[7]);
    unpack2(b.x, v[8], v[9]);
    unpack2(b.y, v[10], v[11]);
}

// one edge: logit -> DPP group reduce -> exp2 (log2e pre-folded into av)
#define PROCESS(FV)                                                         \
    do {                                                                    \
        float t = 0.f;                                                      \
        _Pragma("unroll") for (int j = 0; j < 12; ++j) {                    \
            float u = FV[j] + fdv[j];                                       \
            u = fmaxf(u, 0.2f * u);                                         \
            t = fmaf(u, av[j], t);                                          \
        }                                                                   \
        t = group_sum<G>(t);                                                \
        float ex = exp2f(t);                                                \
        denom += ex;                                                        \
        _Pragma("unroll") for (int j = 0; j < 12; ++j)                      \
            agg[j] = fmaf(ex, FV[j], agg[j]);                               \
    } while (0)

template <int H>
__global__ __launch_bounds__(256) void gat_node_kernel(
    const unsigned short* __restrict__ fs, const unsigned short* __restrict__ fd,
    const int* __restrict__ row_start, const int* __restrict__ csr_src,
    const float* __restrict__ attn, const float* __restrict__ resid,
    const float* __restrict__ ln_w, const float* __restrict__ ln_b,
    float* __restrict__ outf, __hip_bfloat16* __restrict__ outb, int n_nodes) {
    constexpr int G = 64 / H;
    int wave = threadIdx.x >> 6;
    int lane = threadIdx.x & 63;
    int node = blockIdx.x * 4 + wave;
    if (node >= n_nodes) return;
    int hh = lane >> 3, jj = lane & 7;
    int offA = 96 * hh + 8 * jj;        // 8 dims, 16B-aligned
    int offB = 96 * hh + 64 + 4 * jj;   // 4 dims, 8B-aligned

    float fdv[12], av[12], agg[12];
    load12d(fd + (size_t)node * DIM, offA, offB, fdv);
    {
        const float LOG2E = 1.44269504f;  // exp(t) == exp2(t*log2e)
        float4 qa0 = *reinterpret_cast<const float4*>(attn + offA);
        float4 qa1 = *reinterpret_cast<const float4*>(attn + offA + 4);
        float4 qb  = *reinterpret_cast<const float4*>(attn + offB);
        av[0] = qa0.x * LOG2E; av[1] = qa0.y * LOG2E;
        av[2] = qa0.z * LOG2E; av[3] = qa0.w * LOG2E;
        av[4] = qa1.x * LOG2E; av[5] = qa1.y * LOG2E;
        av[6] = qa1.z * LOG2E; av[7] = qa1.w * LOG2E;
        av[8] = qb.x * LOG2E;  av[9] = qb.y * LOG2E;
        av[10] = qb.z * LOG2E; av[11] = qb.w * LOG2E;
    }
#pragma unroll
    for (int j = 0; j < 12; ++j) agg[j] = 0.f;

    int p0 = row_start[node], p1 = row_start[node + 1];
    int np = p1 - p0;
    float denom = 0.f;

    const int* ip = csr_src + p0;

    float fvA[12], fvB[12];
    if (np > 0) load12d(fs + (size_t)ip[0] * DIM, offA, offB, fvA);
    if (np > 1) load12d(fs + (size_t)ip[1] * DIM, offA, offB, fvB);

    int i = 0;
    for (; i + 2 <= np; i += 2) {
        PROCESS(fvA);
        if (i + 2 < np) load12d(fs + (size_t)ip[i + 2] * DIM, offA, offB, fvA);
        PROCESS(fvB);
        if (i + 3 < np) load12d(fs + (size_t)ip[i + 3] * DIM, offA, offB, fvB);
    }
    if (i < np) PROCESS(fvA);

    float inv = (denom > 0.f) ? 1.0f / denom : 0.f;
    float vals[12];
#pragma unroll
    for (int j = 0; j < 12; ++j) {
        float v = agg[j] * inv;
        vals[j] = (v > 0.f) ? v : expm1f(v);
    }
    if (resid != nullptr) {
        const float* rp = resid + (size_t)node * DIM;
        float4 q0 = *reinterpret_cast<const float4*>(rp + offA);
        float4 q1 = *reinterpret_cast<const float4*>(rp + offA + 4);
        float4 q2 = *reinterpret_cast<const float4*>(rp + offB);
        vals[0] += q0.x; vals[1] += q0.y; vals[2] += q0.z; vals[3] += q0.w;
        vals[4] += q1.x; vals[5] += q1.y; vals[6] += q1.z; vals[7] += q1.w;
        vals[8] += q2.x; vals[9] += q2.y; vals[10] += q2.z; vals[11] += q2.w;
    }
    float s1 = 0.f;
#pragma unroll
    for (int j = 0; j < 12; ++j) s1 += vals[j];
    s1 = group_sum<64>(s1);
    float mu = s1 * (1.0f / DIM);
    float s2 = 0.f;
#pragma unroll
    for (int j = 0; j < 12; ++j) {
        float dlt = vals[j] - mu;
        s2 = fmaf(dlt, dlt, s2);
    }
    s2 = group_sum<64>(s2);
    float rs = rsqrtf(s2 * (1.0f / DIM) + 1e-5f);

    float wv[12], bv[12];
    {
        float4 q0 = *reinterpret_cast<const float4*>(ln_w + offA);
        float4 q1 = *reinterpret_cast<const float4*>(ln_w + offA + 4);
        float4 q2 = *reinterpret_cast<const float4*>(ln_w + offB);
        wv[0] = q0.x; wv[1] = q0.y; wv[2] = q0.z; wv[3] = q0.w;
        wv[4] = q1.x; wv[5] = q1.y; wv[6] = q1.z; wv[7] = q1.w;
        wv[8] = q2.x; wv[9] = q2.y; wv[10] = q2.z; wv[11] = q2.w;
        float4 r0 = *reinterpret_cast<const float4*>(ln_b + offA);
        float4 r1 = *reinterpret_cast<const float4*>(ln_b + offA + 4);
        float4 r2 = *reinterpret_cast<const float4*>(ln_b + offB);
        bv[0] = r0.x; bv[1] = r0.y; bv[2] = r0.z; bv[3] = r0.w;
        bv[4] = r1.x; bv[5] = r1.y; bv[6] = r1.z; bv[7] = r1.w;
        bv[8] = r2.x; bv[9] = r2.y; bv[10] = r2.z; bv[11] = r2.w;
    }
    float o[12];
#pragma unroll
    for (int j = 0; j < 12; ++j)
        o[j] = (vals[j] - mu) * rs * wv[j] + bv[j];

    if (outf != nullptr) {
        float* op = outf + (size_t)node * DIM;
        *reinterpret_cast<float4*>(op + offA) =
            make_float4(o[0], o[1], o[2], o[3]);
        *reinterpret_cast<float4*>(op + offA + 4) =
            make_float4(o[4], o[5], o[6], o[7]);
        *reinterpret_cast<float4*>(op + offB) =
            make_float4(o[8], o[9], o[10], o[11]);
    }
    if (outb != nullptr) {
        __hip_bfloat16 hb[12];
#pragma unroll
        for (int j = 0; j < 12; ++j) hb[j] = __float2bfloat16(o[j]);
        unsigned short* op = (unsigned short*)outb + (size_t)node * DIM;
        *reinterpret_cast<uint4*>(op + offA) = *reinterpret_cast<uint4*>(&hb[0]);
        *reinterpret_cast<uint2*>(op + offB) = *reinterpret_cast<uint2*>(&hb[8]);
    }
}

// ---------------------------------------------------------------------------
extern "C" void kernel_launch(void* const* d_in, const int* in_sizes, int n_in,
                              void* d_out, int out_size, void* d_ws, size_t ws_size,
                              hipStream_t stream) {
    const float* x     = (const float*)d_in[0];
    const int*   src   = (const int*)d_in[1];
    const int*   dst   = (const int*)d_in[2];
    const float* W1s   = (const float*)d_in[3];
    const float* b1s   = (const float*)d_in[4];
    const float* W1d   = (const float*)d_in[5];
    const float* b1d   = (const float*)d_in[6];
    const float* attn1 = (const float*)d_in[7];
    const float* ln1w  = (const float*)d_in[8];
    const float* ln1b  = (const float*)d_in[9];
    const float* Wos   = (const float*)d_in[10];
    const float* bos   = (const float*)d_in[11];
    const float* Wod   = (const float*)d_in[12];
    const float* bod   = (const float*)d_in[13];
    const float* attno = (const float*)d_in[14];
    const float* lnow  = (const float*)d_in[15];
    const float* lnob  = (const float*)d_in[16];
    float* out = (float*)d_out;

    const int N = in_sizes[0] / DIM;   // 20000
    const int E = in_sizes[1];         // 320000

    __hip_bfloat16* fsb = (__hip_bfloat16*)d_ws;
    __hip_bfloat16* fdb = fsb + (size_t)N * DIM;
    __hip_bfloat16* Xb  = fdb + (size_t)N * DIM;
    __hip_bfloat16* W1t = Xb + (size_t)N * DIM;
    __hip_bfloat16* Wot = W1t + (size_t)2 * DIM * DIM;
    int* csr_src   = (int*)(Wot + (size_t)2 * DIM * DIM);
    int* row_start = csr_src + E;
    int* cursor    = row_start + (N + 1);
    int* deg       = cursor + N;

    // --- CSR by dst (shared by both layers)
    hipMemsetAsync(deg, 0, (size_t)N * sizeof(int), stream);
    hist_kernel<<<(E + 255) / 256, 256, 0, stream>>>(dst, deg, E);
    scan_kernel<<<1, 1024, 0, stream>>>(deg, row_start, cursor, N);
    scatter_kernel<<<(E + 255) / 256, 256, 0, stream>>>(src, dst, cursor, csr_src, E);

    // --- weight transposes (f32 -> bf16, [K][N] -> [N][K])
    dim3 tg(DIM / 32, DIM / 32);
    transpose_bf16_kernel<<<tg, 256, 0, stream>>>(W1s, W1t, DIM, DIM);
    transpose_bf16_kernel<<<tg, 256, 0, stream>>>(W1d, W1t + (size_t)DIM * DIM, DIM, DIM);
    transpose_bf16_kernel<<<tg, 256, 0, stream>>>(Wos, Wot, DIM, DIM);
    transpose_bf16_kernel<<<tg, 256, 0, stream>>>(Wod, Wot + (size_t)DIM * DIM, DIM, DIM);

    const int n8 = N * DIM / 8;
    const int mt = (N + 127) / 128;
    const int nwg = mt * 12;  // 1D swizzled grid

    // --- layer 1: GEMM -> gat (writes bf16 h straight into Xb for layer 2)
    conv_bf16_kernel<<<(n8 + 255) / 256, 256, 0, stream>>>(x, Xb, n8);
    gemm_mfma_dual_kernel<<<nwg, 256, 0, stream>>>(
        (const bf16_t*)Xb, (const bf16_t*)W1t, b1s, b1d, fsb, fdb, N);
    gat_node_kernel<8><<<(N + 3) / 4, 256, 0, stream>>>(
        (const unsigned short*)fsb, (const unsigned short*)fdb, row_start, csr_src,
        attn1, x, ln1w, ln1b, nullptr, Xb, N);

    // --- layer 2: GEMM -> gat -> final f32 out
    gemm_mfma_dual_kernel<<<nwg, 256, 0, stream>>>(
        (const bf16_t*)Xb, (const bf16_t*)Wot, bos, bod, fsb, fdb, N);
    gat_node_kernel<1><<<(N + 3) / 4, 256, 0, stream>>>(
        (const unsigned short*)fsb, (const unsigned short*)fdb, row_start, csr_src,
        attno, nullptr, lnow, lnob, out, nullptr, N);
}

// Round 12
// 414.813 us; speedup vs baseline: 1.3252x; 1.1151x over previous
//
#include <hip/hip_runtime.h>
#include <hip/hip_bf16.h>
#include <math.h>

#define DIM 768

typedef __bf16 bf16_t;
typedef __attribute__((ext_vector_type(8))) __bf16 bf16x8;
typedef __attribute__((ext_vector_type(4))) float f32x4;

#define GLOAD_LDS16(g, l)                                                  \
    __builtin_amdgcn_global_load_lds(                                      \
        (const __attribute__((address_space(1))) void*)(g),                \
        (__attribute__((address_space(3))) void*)(l), 16, 0, 0)

__device__ __forceinline__ float bf2f(unsigned short u) {
    union { unsigned int i; float f; } x;
    x.i = ((unsigned int)u) << 16;
    return x.f;
}

// ---------------------------------------------------------------------------
// DPP-based group sum (VALU-only within 16 lanes; shfl beyond)
// ---------------------------------------------------------------------------
template <int CTRL>
__device__ __forceinline__ float dpp_add(float v) {
    int s = __builtin_amdgcn_update_dpp(0, __float_as_int(v), CTRL, 0xF, 0xF, true);
    return v + __int_as_float(s);
}

template <int G>
__device__ __forceinline__ float group_sum(float t) {
    t = dpp_add<0xB1>(t);                         // quad_perm xor1
    t = dpp_add<0x4E>(t);                         // quad_perm xor2
    t = dpp_add<0x141>(t);                        // row_half_mirror: 8-group
    if constexpr (G >= 16) t = dpp_add<0x140>(t); // row_mirror: 16-group
    if constexpr (G >= 32) t += __shfl_xor(t, 16, 64);
    if constexpr (G >= 64) t += __shfl_xor(t, 32, 64);
    return t;
}

// ---------------------------------------------------------------------------
// CSR build
// ---------------------------------------------------------------------------
__global__ __launch_bounds__(256) void hist_kernel(const int* __restrict__ dst,
                                                   int* __restrict__ deg, int E) {
    int e = blockIdx.x * 256 + threadIdx.x;
    if (e < E) atomicAdd(&deg[dst[e]], 1);
}

__global__ __launch_bounds__(1024) void scan_kernel(const int* __restrict__ deg,
                                                    int* __restrict__ row_start,
                                                    int* __restrict__ cursor, int n) {
    __shared__ int sh[1024];
    __shared__ int carry_sh;
    int tid = threadIdx.x;
    if (tid == 0) carry_sh = 0;
    __syncthreads();
    for (int base = 0; base < n; base += 1024) {
        int i = base + tid;
        int v = (i < n) ? deg[i] : 0;
        sh[tid] = v;
        __syncthreads();
        for (int off = 1; off < 1024; off <<= 1) {
            int t = (tid >= off) ? sh[tid - off] : 0;
            __syncthreads();
            sh[tid] += t;
            __syncthreads();
        }
        int incl = sh[tid];
        int carry = carry_sh;
        int excl = carry + incl - v;
        if (i < n) { row_start[i] = excl; cursor[i] = excl; }
        __syncthreads();
        if (tid == 1023) carry_sh = carry + incl;
        __syncthreads();
    }
    if (tid == 0) row_start[n] = carry_sh;
}

__global__ __launch_bounds__(256) void scatter_kernel(const int* __restrict__ src,
                                                      const int* __restrict__ dst,
                                                      int* __restrict__ cursor,
                                                      int* __restrict__ csr_src, int E) {
    int e = blockIdx.x * 256 + threadIdx.x;
    if (e < E) {
        int p = atomicAdd(&cursor[dst[e]], 1);
        csr_src[p] = src[e];
    }
}

// ---------------------------------------------------------------------------
// fp32 -> bf16 elementwise convert (8 elems/thread)
// ---------------------------------------------------------------------------
__global__ __launch_bounds__(256) void conv_bf16_kernel(const float* __restrict__ in,
                                                        __hip_bfloat16* __restrict__ out,
                                                        int n8) {
    int i = blockIdx.x * 256 + threadIdx.x;
    if (i >= n8) return;
    const float4* p = reinterpret_cast<const float4*>(in + (size_t)i * 8);
    float4 a = p[0], b = p[1];
    __hip_bfloat16 v[8];
    v[0] = __float2bfloat16(a.x); v[1] = __float2bfloat16(a.y);
    v[2] = __float2bfloat16(a.z); v[3] = __float2bfloat16(a.w);
    v[4] = __float2bfloat16(b.x); v[5] = __float2bfloat16(b.y);
    v[6] = __float2bfloat16(b.z); v[7] = __float2bfloat16(b.w);
    *reinterpret_cast<uint4*>(out + (size_t)i * 8) = *reinterpret_cast<uint4*>(v);
}

// ---------------------------------------------------------------------------
// 4x batched W [768][768] f32 -> Wt [768][768] bf16 transpose (z = matrix id)
// ---------------------------------------------------------------------------
__global__ __launch_bounds__(256) void transpose4_bf16_kernel(
    const float* __restrict__ W0, const float* __restrict__ W1,
    const float* __restrict__ W2, const float* __restrict__ W3,
    __hip_bfloat16* __restrict__ Wt) {   // Wt: 4 contiguous 768x768 outputs
    __shared__ float tile[32][33];
    int z = blockIdx.z;
    const float* W = (z == 0) ? W0 : (z == 1) ? W1 : (z == 2) ? W2 : W3;
    __hip_bfloat16* O = Wt + (size_t)z * DIM * DIM;
    int bk = blockIdx.x * 32, bn = blockIdx.y * 32;
    int tx = threadIdx.x & 31, ty = threadIdx.x >> 5;  // 32 x 8
#pragma unroll
    for (int r = ty; r < 32; r += 8)
        tile[r][tx] = W[(size_t)(bk + r) * DIM + bn + tx];
    __syncthreads();
#pragma unroll
    for (int r = ty; r < 32; r += 8)
        O[(size_t)(bn + r) * DIM + bk + tx] = __float2bfloat16(tile[tx][r]);
}

// ---------------------------------------------------------------------------
// Dual bf16 MFMA GEMM: BM=256 x BN=128, BK=64, 512 threads (8 waves, 4x2),
// per-wave 64x64 output. XOR-swizzled LDS via pre-swizzled global source.
// 1D grid with bijective XCD-chunk swizzle, bn fastest.
// ---------------------------------------------------------------------------
__global__ __launch_bounds__(512) void gemm_mfma_dual_kernel(
    const bf16_t* __restrict__ Xb,   // [M][768]
    const bf16_t* __restrict__ Wt,   // [1536][768]
    const float* __restrict__ b1, const float* __restrict__ b2,
    __hip_bfloat16* __restrict__ C1, __hip_bfloat16* __restrict__ C2, int M) {
    __shared__ __align__(16) bf16_t As[256 * 64];   // 32 KB
    __shared__ __align__(16) bf16_t Bs[128 * 64];   // 16 KB

    const int nwg = gridDim.x;
    const int o = blockIdx.x;
    const int q = nwg >> 3, r = nwg & 7;
    const int xcd = o & 7, jj = o >> 3;
    const int lin = (xcd < r ? xcd * (q + 1) : r * (q + 1) + (xcd - r) * q) + jj;
    const int bn = (lin % 12) * 128;
    const int bm = (lin / 12) * 256;

    const int tid = threadIdx.x;
    const int lane = tid & 63;
    const int w = tid >> 6;         // 0..7
    const int wrow = w >> 1;        // 0..3 : 64-row band
    const int wcol = w & 1;         // 0..1 : 64-col band

    f32x4 acc[4][4];
    {
        const float* bp = (bn < DIM) ? b1 : b2;
        int cb = (bn < DIM) ? bn : bn - DIM;
#pragma unroll
        for (int ni = 0; ni < 4; ++ni) {
            float bv = bp[cb + wcol * 64 + ni * 16 + (lane & 15)];
#pragma unroll
            for (int mi = 0; mi < 4; ++mi) acc[mi][ni] = f32x4{bv, bv, bv, bv};
        }
    }

    const int trow = tid >> 3;          // 0..63 : tile row within a pass
    const int tcol = (tid & 7) * 8;     // element col before swizzle

    for (int k0 = 0; k0 < DIM; k0 += 64) {
        // A: 256 rows in 4 passes of 64 rows (whole block)
#pragma unroll
        for (int p = 0; p < 4; ++p) {
            int rr = p * 64 + trow;
            int col = tcol ^ ((rr & 7) << 3);   // pre-swizzled source (rule #21)
            int rg = bm + rr; rg = rg < M ? rg : M - 1;
            GLOAD_LDS16(Xb + (size_t)rg * DIM + k0 + col, &As[(p * 64 + w * 8) * 64]);
        }
        // B: 128 rows in 2 passes
#pragma unroll
        for (int p = 0; p < 2; ++p) {
            int rr = p * 64 + trow;
            int col = tcol ^ ((rr & 7) << 3);
            GLOAD_LDS16(Wt + (size_t)(bn + rr) * DIM + k0 + col, &Bs[(p * 64 + w * 8) * 64]);
        }
        __syncthreads();

#pragma unroll
        for (int kk = 0; kk < 2; ++kk) {
            bf16x8 af[4], bfr[4];
            int ke = kk * 32 + (lane >> 4) * 8;
#pragma unroll
            for (int mi = 0; mi < 4; ++mi) {
                int rr = wrow * 64 + mi * 16 + (lane & 15);
                af[mi] = *(const bf16x8*)&As[rr * 64 + (ke ^ ((rr & 7) << 3))];
            }
#pragma unroll
            for (int ni = 0; ni < 4; ++ni) {
                int rr = wcol * 64 + ni * 16 + (lane & 15);
                bfr[ni] = *(const bf16x8*)&Bs[rr * 64 + (ke ^ ((rr & 7) << 3))];
            }
#pragma unroll
            for (int mi = 0; mi < 4; ++mi)
#pragma unroll
                for (int ni = 0; ni < 4; ++ni)
                    acc[mi][ni] = __builtin_amdgcn_mfma_f32_16x16x32_bf16(
                        af[mi], bfr[ni], acc[mi][ni], 0, 0, 0);
        }
        __syncthreads();
    }

    __hip_bfloat16* C = (bn < DIM) ? C1 : C2;
    int cb = (bn < DIM) ? bn : bn - DIM;
#pragma unroll
    for (int mi = 0; mi < 4; ++mi) {
#pragma unroll
        for (int j = 0; j < 4; ++j) {
            int row = bm + wrow * 64 + mi * 16 + (lane >> 4) * 4 + j;
            if (row < M) {
#pragma unroll
                for (int ni = 0; ni < 4; ++ni) {
                    int col = cb + wcol * 64 + ni * 16 + (lane & 15);
                    C[(size_t)row * DIM + col] = __float2bfloat16(acc[mi][ni][j]);
                }
            }
        }
    }
}

// ---------------------------------------------------------------------------
// Per-node GAT: round-6 structure exactly (one wave/node, strided load12,
// 2-deep prefetch, max-free softmax, DPP reduce) + exp2 with log2e folded.
// ---------------------------------------------------------------------------
__device__ __forceinline__ void load12(const unsigned short* __restrict__ p, float* v) {
    ushort4 a = *reinterpret_cast<const ushort4*>(p);
    ushort4 b = *reinterpret_cast<const ushort4*>(p + 4);
    ushort4 c = *reinterpret_cast<const ushort4*>(p + 8);
    v[0] = bf2f(a.x); v[1] = bf2f(a.y); v[2] = bf2f(a.z); v[3] = bf2f(a.w);
    v[4] = bf2f(b.x); v[5] = bf2f(b.y); v[6] = bf2f(b.z); v[7] = bf2f(b.w);
    v[8] = bf2f(c.x); v[9] = bf2f(c.y); v[10] = bf2f(c.z); v[11] = bf2f(c.w);
}

// one edge: logit -> DPP group reduce -> exp2 (log2e pre-folded into av)
#define PROCESS(FV)                                                         \
    do {                                                                    \
        float t = 0.f;                                                      \
        _Pragma("unroll") for (int j = 0; j < 12; ++j) {                    \
            float u = FV[j] + fdv[j];                                       \
            u = fmaxf(u, 0.2f * u);                                         \
            t = fmaf(u, av[j], t);                                          \
        }                                                                   \
        t = group_sum<G>(t);                                                \
        float ex = exp2f(t);                                                \
        denom += ex;                                                        \
        _Pragma("unroll") for (int j = 0; j < 12; ++j)                      \
            agg[j] = fmaf(ex, FV[j], agg[j]);                               \
    } while (0)

template <int H>
__global__ __launch_bounds__(256) void gat_node_kernel(
    const unsigned short* __restrict__ fs, const unsigned short* __restrict__ fd,
    const int* __restrict__ row_start, const int* __restrict__ csr_src,
    const float* __restrict__ attn, const float* __restrict__ resid,
    const float* __restrict__ ln_w, const float* __restrict__ ln_b,
    float* __restrict__ outf, __hip_bfloat16* __restrict__ outb, int n_nodes) {
    constexpr int G = 64 / H;
    int wave = threadIdx.x >> 6;
    int lane = threadIdx.x & 63;
    int node = blockIdx.x * 4 + wave;
    if (node >= n_nodes) return;
    int d0 = lane * 12;

    float fdv[12], av[12], agg[12];
    load12(fd + (size_t)node * DIM + d0, fdv);
    {
        const float* ap = attn + d0;
        const float LOG2E = 1.44269504f;  // exp(t) == exp2(t*log2e)
#pragma unroll
        for (int j = 0; j < 12; ++j) av[j] = ap[j] * LOG2E;
    }
#pragma unroll
    for (int j = 0; j < 12; ++j) agg[j] = 0.f;

    int p0 = row_start[node], p1 = row_start[node + 1];
    int np = p1 - p0;
    float denom = 0.f;

    const unsigned short* fsl = fs + d0;
    const int* ip = csr_src + p0;

    float fvA[12], fvB[12];
    if (np > 0) load12(fsl + (size_t)ip[0] * DIM, fvA);
    if (np > 1) load12(fsl + (size_t)ip[1] * DIM, fvB);

    int i = 0;
    for (; i + 2 <= np; i += 2) {
        PROCESS(fvA);
        if (i + 2 < np) load12(fsl + (size_t)ip[i + 2] * DIM, fvA);
        PROCESS(fvB);
        if (i + 3 < np) load12(fsl + (size_t)ip[i + 3] * DIM, fvB);
    }
    if (i < np) PROCESS(fvA);

    float inv = (denom > 0.f) ? 1.0f / denom : 0.f;
    float vals[12];
#pragma unroll
    for (int j = 0; j < 12; ++j) {
        float v = agg[j] * inv;
        vals[j] = (v > 0.f) ? v : expm1f(v);
    }
    if (resid != nullptr) {
        const float4* p = reinterpret_cast<const float4*>(resid + (size_t)node * DIM + d0);
        float4 q0 = p[0], q1 = p[1], q2 = p[2];
        vals[0] += q0.x; vals[1] += q0.y; vals[2] += q0.z; vals[3] += q0.w;
        vals[4] += q1.x; vals[5] += q1.y; vals[6] += q1.z; vals[7] += q1.w;
        vals[8] += q2.x; vals[9] += q2.y; vals[10] += q2.z; vals[11] += q2.w;
    }
    float s1 = 0.f;
#pragma unroll
    for (int j = 0; j < 12; ++j) s1 += vals[j];
    s1 = group_sum<64>(s1);
    float mu = s1 * (1.0f / DIM);
    float s2 = 0.f;
#pragma unroll
    for (int j = 0; j < 12; ++j) {
        float dlt = vals[j] - mu;
        s2 = fmaf(dlt, dlt, s2);
    }
    s2 = group_sum<64>(s2);
    float rs = rsqrtf(s2 * (1.0f / DIM) + 1e-5f);

    float wv[12], bv[12];
    {
        const float4* p = reinterpret_cast<const float4*>(ln_w + d0);
        float4 q0 = p[0], q1 = p[1], q2 = p[2];
        wv[0] = q0.x; wv[1] = q0.y; wv[2] = q0.z; wv[3] = q0.w;
        wv[4] = q1.x; wv[5] = q1.y; wv[6] = q1.z; wv[7] = q1.w;
        wv[8] = q2.x; wv[9] = q2.y; wv[10] = q2.z; wv[11] = q2.w;
        const float4* pb = reinterpret_cast<const float4*>(ln_b + d0);
        float4 r0 = pb[0], r1 = pb[1], r2 = pb[2];
        bv[0] = r0.x; bv[1] = r0.y; bv[2] = r0.z; bv[3] = r0.w;
        bv[4] = r1.x; bv[5] = r1.y; bv[6] = r1.z; bv[7] = r1.w;
        bv[8] = r2.x; bv[9] = r2.y; bv[10] = r2.z; bv[11] = r2.w;
    }
    float o[12];
#pragma unroll
    for (int j = 0; j < 12; ++j)
        o[j] = (vals[j] - mu) * rs * wv[j] + bv[j];

    if (outf != nullptr) {
        float* op = outf + (size_t)node * DIM + d0;
#pragma unroll
        for (int qq = 0; qq < 3; ++qq) {
            float4 t4 = make_float4(o[qq * 4 + 0], o[qq * 4 + 1], o[qq * 4 + 2], o[qq * 4 + 3]);
            *reinterpret_cast<float4*>(op + qq * 4) = t4;
        }
    }
    if (outb != nullptr) {
        __hip_bfloat16 hb[12];
#pragma unroll
        for (int j = 0; j < 12; ++j) hb[j] = __float2bfloat16(o[j]);
        unsigned short* op = (unsigned short*)outb + (size_t)node * DIM + d0;
#pragma unroll
        for (int qq = 0; qq < 3; ++qq)
            *reinterpret_cast<ushort4*>(op + qq * 4) =
                *reinterpret_cast<ushort4*>(&hb[qq * 4]);
    }
}

// ---------------------------------------------------------------------------
extern "C" void kernel_launch(void* const* d_in, const int* in_sizes, int n_in,
                              void* d_out, int out_size, void* d_ws, size_t ws_size,
                              hipStream_t stream) {
    const float* x     = (const float*)d_in[0];
    const int*   src   = (const int*)d_in[1];
    const int*   dst   = (const int*)d_in[2];
    const float* W1s   = (const float*)d_in[3];
    const float* b1s   = (const float*)d_in[4];
    const float* W1d   = (const float*)d_in[5];
    const float* b1d   = (const float*)d_in[6];
    const float* attn1 = (const float*)d_in[7];
    const float* ln1w  = (const float*)d_in[8];
    const float* ln1b  = (const float*)d_in[9];
    const float* Wos   = (const float*)d_in[10];
    const float* bos   = (const float*)d_in[11];
    const float* Wod   = (const float*)d_in[12];
    const float* bod   = (const float*)d_in[13];
    const float* attno = (const float*)d_in[14];
    const float* lnow  = (const float*)d_in[15];
    const float* lnob  = (const float*)d_in[16];
    float* out = (float*)d_out;

    const int N = in_sizes[0] / DIM;   // 20000
    const int E = in_sizes[1];         // 320000

    __hip_bfloat16* fsb = (__hip_bfloat16*)d_ws;
    __hip_bfloat16* fdb = fsb + (size_t)N * DIM;
    __hip_bfloat16* Xb  = fdb + (size_t)N * DIM;
    __hip_bfloat16* W1t = Xb + (size_t)N * DIM;   // 4 contiguous 768x768 mats
    __hip_bfloat16* Wot = W1t + (size_t)2 * DIM * DIM;
    int* csr_src   = (int*)(Wot + (size_t)2 * DIM * DIM);
    int* row_start = csr_src + E;
    int* cursor    = row_start + (N + 1);
    int* deg       = cursor + N;

    // --- CSR by dst (shared by both layers)
    hipMemsetAsync(deg, 0, (size_t)N * sizeof(int), stream);
    hist_kernel<<<(E + 255) / 256, 256, 0, stream>>>(dst, deg, E);
    scan_kernel<<<1, 1024, 0, stream>>>(deg, row_start, cursor, N);
    scatter_kernel<<<(E + 255) / 256, 256, 0, stream>>>(src, dst, cursor, csr_src, E);

    // --- weight transposes, all 4 in one dispatch (f32 -> bf16, [K][N] -> [N][K])
    dim3 tg(DIM / 32, DIM / 32, 4);
    transpose4_bf16_kernel<<<tg, 256, 0, stream>>>(W1s, W1d, Wos, Wod, W1t);

    const int n8 = N * DIM / 8;
    const int mt = (N + 255) / 256;
    const int nwg = mt * 12;  // 1D swizzled grid (256x128 tiles)

    // --- layer 1: GEMM -> gat (writes bf16 h straight into Xb for layer 2)
    conv_bf16_kernel<<<(n8 + 255) / 256, 256, 0, stream>>>(x, Xb, n8);
    gemm_mfma_dual_kernel<<<nwg, 512, 0, stream>>>(
        (const bf16_t*)Xb, (const bf16_t*)W1t, b1s, b1d, fsb, fdb, N);
    gat_node_kernel<8><<<(N + 3) / 4, 256, 0, stream>>>(
        (const unsigned short*)fsb, (const unsigned short*)fdb, row_start, csr_src,
        attn1, x, ln1w, ln1b, nullptr, Xb, N);

    // --- layer 2: GEMM -> gat -> final f32 out
    gemm_mfma_dual_kernel<<<nwg, 512, 0, stream>>>(
        (const bf16_t*)Xb, (const bf16_t*)Wot, bos, bod, fsb, fdb, N);
    gat_node_kernel<1><<<(N + 3) / 4, 256, 0, stream>>>(
        (const unsigned short*)fsb, (const unsigned short*)fdb, row_start, csr_src,
        attno, nullptr, lnow, lnob, out, nullptr, N);
}

// Round 13
// 410.155 us; speedup vs baseline: 1.3402x; 1.0114x over previous
//
#include <hip/hip_runtime.h>
#include <hip/hip_bf16.h>
#include <math.h>

#define DIM 768

typedef __bf16 bf16_t;
typedef __attribute__((ext_vector_type(8))) __bf16 bf16x8;
typedef __attribute__((ext_vector_type(4))) float f32x4;

#define GLOAD_LDS16(g, l)                                                  \
    __builtin_amdgcn_global_load_lds(                                      \
        (const __attribute__((address_space(1))) void*)(g),                \
        (__attribute__((address_space(3))) void*)(l), 16, 0, 0)

__device__ __forceinline__ float bf2f(unsigned short u) {
    union { unsigned int i; float f; } x;
    x.i = ((unsigned int)u) << 16;
    return x.f;
}

// ---------------------------------------------------------------------------
// DPP-based group sum (VALU-only within 16 lanes; shfl beyond)
// ---------------------------------------------------------------------------
template <int CTRL>
__device__ __forceinline__ float dpp_add(float v) {
    int s = __builtin_amdgcn_update_dpp(0, __float_as_int(v), CTRL, 0xF, 0xF, true);
    return v + __int_as_float(s);
}

template <int G>
__device__ __forceinline__ float group_sum(float t) {
    t = dpp_add<0xB1>(t);                         // quad_perm xor1
    t = dpp_add<0x4E>(t);                         // quad_perm xor2
    t = dpp_add<0x141>(t);                        // row_half_mirror: 8-group
    if constexpr (G >= 16) t = dpp_add<0x140>(t); // row_mirror: 16-group
    if constexpr (G >= 32) t += __shfl_xor(t, 16, 64);
    if constexpr (G >= 64) t += __shfl_xor(t, 32, 64);
    return t;
}

// ---------------------------------------------------------------------------
// CSR build
// ---------------------------------------------------------------------------
__global__ __launch_bounds__(256) void hist_kernel(const int* __restrict__ dst,
                                                   int* __restrict__ deg, int E) {
    int e = blockIdx.x * 256 + threadIdx.x;
    if (e < E) atomicAdd(&deg[dst[e]], 1);
}

__global__ __launch_bounds__(1024) void scan_kernel(const int* __restrict__ deg,
                                                    int* __restrict__ row_start,
                                                    int* __restrict__ cursor, int n) {
    __shared__ int sh[1024];
    __shared__ int carry_sh;
    int tid = threadIdx.x;
    if (tid == 0) carry_sh = 0;
    __syncthreads();
    for (int base = 0; base < n; base += 1024) {
        int i = base + tid;
        int v = (i < n) ? deg[i] : 0;
        sh[tid] = v;
        __syncthreads();
        for (int off = 1; off < 1024; off <<= 1) {
            int t = (tid >= off) ? sh[tid - off] : 0;
            __syncthreads();
            sh[tid] += t;
            __syncthreads();
        }
        int incl = sh[tid];
        int carry = carry_sh;
        int excl = carry + incl - v;
        if (i < n) { row_start[i] = excl; cursor[i] = excl; }
        __syncthreads();
        if (tid == 1023) carry_sh = carry + incl;
        __syncthreads();
    }
    if (tid == 0) row_start[n] = carry_sh;
}

__global__ __launch_bounds__(256) void scatter_kernel(const int* __restrict__ src,
                                                      const int* __restrict__ dst,
                                                      int* __restrict__ cursor,
                                                      int* __restrict__ csr_src, int E) {
    int e = blockIdx.x * 256 + threadIdx.x;
    if (e < E) {
        int p = atomicAdd(&cursor[dst[e]], 1);
        csr_src[p] = src[e];
    }
}

// ---------------------------------------------------------------------------
// fp32 -> bf16 elementwise convert (8 elems/thread)
// ---------------------------------------------------------------------------
__global__ __launch_bounds__(256) void conv_bf16_kernel(const float* __restrict__ in,
                                                        __hip_bfloat16* __restrict__ out,
                                                        int n8) {
    int i = blockIdx.x * 256 + threadIdx.x;
    if (i >= n8) return;
    const float4* p = reinterpret_cast<const float4*>(in + (size_t)i * 8);
    float4 a = p[0], b = p[1];
    __hip_bfloat16 v[8];
    v[0] = __float2bfloat16(a.x); v[1] = __float2bfloat16(a.y);
    v[2] = __float2bfloat16(a.z); v[3] = __float2bfloat16(a.w);
    v[4] = __float2bfloat16(b.x); v[5] = __float2bfloat16(b.y);
    v[6] = __float2bfloat16(b.z); v[7] = __float2bfloat16(b.w);
    *reinterpret_cast<uint4*>(out + (size_t)i * 8) = *reinterpret_cast<uint4*>(v);
}

// ---------------------------------------------------------------------------
// 4x batched W [768][768] f32 -> Wt [768][768] bf16 transpose (z = matrix id)
// ---------------------------------------------------------------------------
__global__ __launch_bounds__(256) void transpose4_bf16_kernel(
    const float* __restrict__ W0, const float* __restrict__ W1,
    const float* __restrict__ W2, const float* __restrict__ W3,
    __hip_bfloat16* __restrict__ Wt) {   // Wt: 4 contiguous 768x768 outputs
    __shared__ float tile[32][33];
    int z = blockIdx.z;
    const float* W = (z == 0) ? W0 : (z == 1) ? W1 : (z == 2) ? W2 : W3;
    __hip_bfloat16* O = Wt + (size_t)z * DIM * DIM;
    int bk = blockIdx.x * 32, bn = blockIdx.y * 32;
    int tx = threadIdx.x & 31, ty = threadIdx.x >> 5;  // 32 x 8
#pragma unroll
    for (int r = ty; r < 32; r += 8)
        tile[r][tx] = W[(size_t)(bk + r) * DIM + bn + tx];
    __syncthreads();
#pragma unroll
    for (int r = ty; r < 32; r += 8)
        O[(size_t)(bn + r) * DIM + bk + tx] = __float2bfloat16(tile[tx][r]);
}

// ---------------------------------------------------------------------------
// Dual bf16 MFMA GEMM: BM=256 x BN=128, BK=64, 512 threads (8 waves, 4x2),
// per-wave 64x64 output. XOR-swizzled LDS via pre-swizzled global source.
// 1D grid with bijective XCD-chunk swizzle, bn fastest.
// ---------------------------------------------------------------------------
__global__ __launch_bounds__(512) void gemm_mfma_dual_kernel(
    const bf16_t* __restrict__ Xb,   // [M][768]
    const bf16_t* __restrict__ Wt,   // [1536][768]
    const float* __restrict__ b1, const float* __restrict__ b2,
    __hip_bfloat16* __restrict__ C1, __hip_bfloat16* __restrict__ C2, int M) {
    __shared__ __align__(16) bf16_t As[256 * 64];   // 32 KB
    __shared__ __align__(16) bf16_t Bs[128 * 64];   // 16 KB

    const int nwg = gridDim.x;
    const int o = blockIdx.x;
    const int q = nwg >> 3, r = nwg & 7;
    const int xcd = o & 7, jj = o >> 3;
    const int lin = (xcd < r ? xcd * (q + 1) : r * (q + 1) + (xcd - r) * q) + jj;
    const int bn = (lin % 12) * 128;
    const int bm = (lin / 12) * 256;

    const int tid = threadIdx.x;
    const int lane = tid & 63;
    const int w = tid >> 6;         // 0..7
    const int wrow = w >> 1;        // 0..3 : 64-row band
    const int wcol = w & 1;         // 0..1 : 64-col band

    f32x4 acc[4][4];
    {
        const float* bp = (bn < DIM) ? b1 : b2;
        int cb = (bn < DIM) ? bn : bn - DIM;
#pragma unroll
        for (int ni = 0; ni < 4; ++ni) {
            float bv = bp[cb + wcol * 64 + ni * 16 + (lane & 15)];
#pragma unroll
            for (int mi = 0; mi < 4; ++mi) acc[mi][ni] = f32x4{bv, bv, bv, bv};
        }
    }

    const int trow = tid >> 3;          // 0..63 : tile row within a pass
    const int tcol = (tid & 7) * 8;     // element col before swizzle

    for (int k0 = 0; k0 < DIM; k0 += 64) {
        // A: 256 rows in 4 passes of 64 rows (whole block)
#pragma unroll
        for (int p = 0; p < 4; ++p) {
            int rr = p * 64 + trow;
            int col = tcol ^ ((rr & 7) << 3);   // pre-swizzled source (rule #21)
            int rg = bm + rr; rg = rg < M ? rg : M - 1;
            GLOAD_LDS16(Xb + (size_t)rg * DIM + k0 + col, &As[(p * 64 + w * 8) * 64]);
        }
        // B: 128 rows in 2 passes
#pragma unroll
        for (int p = 0; p < 2; ++p) {
            int rr = p * 64 + trow;
            int col = tcol ^ ((rr & 7) << 3);
            GLOAD_LDS16(Wt + (size_t)(bn + rr) * DIM + k0 + col, &Bs[(p * 64 + w * 8) * 64]);
        }
        __syncthreads();

#pragma unroll
        for (int kk = 0; kk < 2; ++kk) {
            bf16x8 af[4], bfr[4];
            int ke = kk * 32 + (lane >> 4) * 8;
#pragma unroll
            for (int mi = 0; mi < 4; ++mi) {
                int rr = wrow * 64 + mi * 16 + (lane & 15);
                af[mi] = *(const bf16x8*)&As[rr * 64 + (ke ^ ((rr & 7) << 3))];
            }
#pragma unroll
            for (int ni = 0; ni < 4; ++ni) {
                int rr = wcol * 64 + ni * 16 + (lane & 15);
                bfr[ni] = *(const bf16x8*)&Bs[rr * 64 + (ke ^ ((rr & 7) << 3))];
            }
#pragma unroll
            for (int mi = 0; mi < 4; ++mi)
#pragma unroll
                for (int ni = 0; ni < 4; ++ni)
                    acc[mi][ni] = __builtin_amdgcn_mfma_f32_16x16x32_bf16(
                        af[mi], bfr[ni], acc[mi][ni], 0, 0, 0);
        }
        __syncthreads();
    }

    __hip_bfloat16* C = (bn < DIM) ? C1 : C2;
    int cb = (bn < DIM) ? bn : bn - DIM;
#pragma unroll
    for (int mi = 0; mi < 4; ++mi) {
#pragma unroll
        for (int j = 0; j < 4; ++j) {
            int row = bm + wrow * 64 + mi * 16 + (lane >> 4) * 4 + j;
            if (row < M) {
#pragma unroll
                for (int ni = 0; ni < 4; ++ni) {
                    int col = cb + wcol * 64 + ni * 16 + (lane & 15);
                    C[(size_t)row * DIM + col] = __float2bfloat16(acc[mi][ni][j]);
                }
            }
        }
    }
}

// ---------------------------------------------------------------------------
// Per-node GAT: EXACT round-6 kernel (48 VGPR, 103 us measured twice).
// One wave per node, strided load12, 2-deep prefetch, max-free softmax,
// DPP group reduce, __expf, float4 attn loads. DO NOT touch registers.
// ---------------------------------------------------------------------------
__device__ __forceinline__ void load12(const unsigned short* __restrict__ p, float* v) {
    ushort4 a = *reinterpret_cast<const ushort4*>(p);
    ushort4 b = *reinterpret_cast<const ushort4*>(p + 4);
    ushort4 c = *reinterpret_cast<const ushort4*>(p + 8);
    v[0] = bf2f(a.x); v[1] = bf2f(a.y); v[2] = bf2f(a.z); v[3] = bf2f(a.w);
    v[4] = bf2f(b.x); v[5] = bf2f(b.y); v[6] = bf2f(b.z); v[7] = bf2f(b.w);
    v[8] = bf2f(c.x); v[9] = bf2f(c.y); v[10] = bf2f(c.z); v[11] = bf2f(c.w);
}

// one edge: logit -> DPP group reduce -> exp -> accumulate
#define PROCESS(FV)                                                         \
    do {                                                                    \
        float t = 0.f;                                                      \
        _Pragma("unroll") for (int j = 0; j < 12; ++j) {                    \
            float u = FV[j] + fdv[j];                                       \
            u = fmaxf(u, 0.2f * u);                                         \
            t = fmaf(u, av[j], t);                                          \
        }                                                                   \
        t = group_sum<G>(t);                                                \
        float ex = __expf(t);                                               \
        denom += ex;                                                        \
        _Pragma("unroll") for (int j = 0; j < 12; ++j)                      \
            agg[j] = fmaf(ex, FV[j], agg[j]);                               \
    } while (0)

template <int H>
__global__ __launch_bounds__(256) void gat_node_kernel(
    const unsigned short* __restrict__ fs, const unsigned short* __restrict__ fd,
    const int* __restrict__ row_start, const int* __restrict__ csr_src,
    const float* __restrict__ attn, const float* __restrict__ resid,
    const float* __restrict__ ln_w, const float* __restrict__ ln_b,
    float* __restrict__ outf, __hip_bfloat16* __restrict__ outb, int n_nodes) {
    constexpr int G = 64 / H;
    int wave = threadIdx.x >> 6;
    int lane = threadIdx.x & 63;
    int node = blockIdx.x * 4 + wave;
    if (node >= n_nodes) return;
    int d0 = lane * 12;

    float fdv[12], av[12], agg[12];
    load12(fd + (size_t)node * DIM + d0, fdv);
    {
        const float4* p = reinterpret_cast<const float4*>(attn + d0);
        float4 q0 = p[0], q1 = p[1], q2 = p[2];
        av[0] = q0.x; av[1] = q0.y; av[2] = q0.z; av[3] = q0.w;
        av[4] = q1.x; av[5] = q1.y; av[6] = q1.z; av[7] = q1.w;
        av[8] = q2.x; av[9] = q2.y; av[10] = q2.z; av[11] = q2.w;
    }
#pragma unroll
    for (int j = 0; j < 12; ++j) agg[j] = 0.f;

    int p0 = row_start[node], p1 = row_start[node + 1];
    int np = p1 - p0;
    float denom = 0.f;

    const unsigned short* fsl = fs + d0;
    const int* ip = csr_src + p0;

    float fvA[12], fvB[12];
    if (np > 0) load12(fsl + (size_t)ip[0] * DIM, fvA);
    if (np > 1) load12(fsl + (size_t)ip[1] * DIM, fvB);

    int i = 0;
    for (; i + 2 <= np; i += 2) {
        PROCESS(fvA);
        if (i + 2 < np) load12(fsl + (size_t)ip[i + 2] * DIM, fvA);
        PROCESS(fvB);
        if (i + 3 < np) load12(fsl + (size_t)ip[i + 3] * DIM, fvB);
    }
    if (i < np) PROCESS(fvA);

    float inv = (denom > 0.f) ? 1.0f / denom : 0.f;
    float vals[12];
#pragma unroll
    for (int j = 0; j < 12; ++j) {
        float v = agg[j] * inv;
        vals[j] = (v > 0.f) ? v : expm1f(v);
    }
    if (resid != nullptr) {
        const float4* p = reinterpret_cast<const float4*>(resid + (size_t)node * DIM + d0);
        float4 q0 = p[0], q1 = p[1], q2 = p[2];
        vals[0] += q0.x; vals[1] += q0.y; vals[2] += q0.z; vals[3] += q0.w;
        vals[4] += q1.x; vals[5] += q1.y; vals[6] += q1.z; vals[7] += q1.w;
        vals[8] += q2.x; vals[9] += q2.y; vals[10] += q2.z; vals[11] += q2.w;
    }
    float s1 = 0.f;
#pragma unroll
    for (int j = 0; j < 12; ++j) s1 += vals[j];
    s1 = group_sum<64>(s1);
    float mu = s1 * (1.0f / DIM);
    float s2 = 0.f;
#pragma unroll
    for (int j = 0; j < 12; ++j) {
        float dlt = vals[j] - mu;
        s2 = fmaf(dlt, dlt, s2);
    }
    s2 = group_sum<64>(s2);
    float rs = rsqrtf(s2 * (1.0f / DIM) + 1e-5f);

    float wv[12], bv[12];
    {
        const float4* p = reinterpret_cast<const float4*>(ln_w + d0);
        float4 q0 = p[0], q1 = p[1], q2 = p[2];
        wv[0] = q0.x; wv[1] = q0.y; wv[2] = q0.z; wv[3] = q0.w;
        wv[4] = q1.x; wv[5] = q1.y; wv[6] = q1.z; wv[7] = q1.w;
        wv[8] = q2.x; wv[9] = q2.y; wv[10] = q2.z; wv[11] = q2.w;
        const float4* pb = reinterpret_cast<const float4*>(ln_b + d0);
        float4 r0 = pb[0], r1 = pb[1], r2 = pb[2];
        bv[0] = r0.x; bv[1] = r0.y; bv[2] = r0.z; bv[3] = r0.w;
        bv[4] = r1.x; bv[5] = r1.y; bv[6] = r1.z; bv[7] = r1.w;
        bv[8] = r2.x; bv[9] = r2.y; bv[10] = r2.z; bv[11] = r2.w;
    }
    float o[12];
#pragma unroll
    for (int j = 0; j < 12; ++j)
        o[j] = (vals[j] - mu) * rs * wv[j] + bv[j];

    if (outf != nullptr) {
        float* op = outf + (size_t)node * DIM + d0;
#pragma unroll
        for (int qq = 0; qq < 3; ++qq) {
            float4 t4 = make_float4(o[qq * 4 + 0], o[qq * 4 + 1], o[qq * 4 + 2], o[qq * 4 + 3]);
            *reinterpret_cast<float4*>(op + qq * 4) = t4;
        }
    }
    if (outb != nullptr) {
        __hip_bfloat16 hb[12];
#pragma unroll
        for (int j = 0; j < 12; ++j) hb[j] = __float2bfloat16(o[j]);
        unsigned short* op = (unsigned short*)outb + (size_t)node * DIM + d0;
#pragma unroll
        for (int qq = 0; qq < 3; ++qq)
            *reinterpret_cast<ushort4*>(op + qq * 4) =
                *reinterpret_cast<ushort4*>(&hb[qq * 4]);
    }
}

// ---------------------------------------------------------------------------
extern "C" void kernel_launch(void* const* d_in, const int* in_sizes, int n_in,
                              void* d_out, int out_size, void* d_ws, size_t ws_size,
                              hipStream_t stream) {
    const float* x     = (const float*)d_in[0];
    const int*   src   = (const int*)d_in[1];
    const int*   dst   = (const int*)d_in[2];
    const float* W1s   = (const float*)d_in[3];
    const float* b1s   = (const float*)d_in[4];
    const float* W1d   = (const float*)d_in[5];
    const float* b1d   = (const float*)d_in[6];
    const float* attn1 = (const float*)d_in[7];
    const float* ln1w  = (const float*)d_in[8];
    const float* ln1b  = (const float*)d_in[9];
    const float* Wos   = (const float*)d_in[10];
    const float* bos   = (const float*)d_in[11];
    const float* Wod   = (const float*)d_in[12];
    const float* bod   = (const float*)d_in[13];
    const float* attno = (const float*)d_in[14];
    const float* lnow  = (const float*)d_in[15];
    const float* lnob  = (const float*)d_in[16];
    float* out = (float*)d_out;

    const int N = in_sizes[0] / DIM;   // 20000
    const int E = in_sizes[1];         // 320000

    __hip_bfloat16* fsb = (__hip_bfloat16*)d_ws;
    __hip_bfloat16* fdb = fsb + (size_t)N * DIM;
    __hip_bfloat16* Xb  = fdb + (size_t)N * DIM;
    __hip_bfloat16* W1t = Xb + (size_t)N * DIM;   // 4 contiguous 768x768 mats
    __hip_bfloat16* Wot = W1t + (size_t)2 * DIM * DIM;
    int* csr_src   = (int*)(Wot + (size_t)2 * DIM * DIM);
    int* row_start = csr_src + E;
    int* cursor    = row_start + (N + 1);
    int* deg       = cursor + N;

    // --- CSR by dst (shared by both layers)
    hipMemsetAsync(deg, 0, (size_t)N * sizeof(int), stream);
    hist_kernel<<<(E + 255) / 256, 256, 0, stream>>>(dst, deg, E);
    scan_kernel<<<1, 1024, 0, stream>>>(deg, row_start, cursor, N);
    scatter_kernel<<<(E + 255) / 256, 256, 0, stream>>>(src, dst, cursor, csr_src, E);

    // --- weight transposes, all 4 in one dispatch (f32 -> bf16, [K][N] -> [N][K])
    dim3 tg(DIM / 32, DIM / 32, 4);
    transpose4_bf16_kernel<<<tg, 256, 0, stream>>>(W1s, W1d, Wos, Wod, W1t);

    const int n8 = N * DIM / 8;
    const int mt = (N + 255) / 256;
    const int nwg = mt * 12;  // 1D swizzled grid (256x128 tiles)

    // --- layer 1: GEMM -> gat (writes bf16 h straight into Xb for layer 2)
    conv_bf16_kernel<<<(n8 + 255) / 256, 256, 0, stream>>>(x, Xb, n8);
    gemm_mfma_dual_kernel<<<nwg, 512, 0, stream>>>(
        (const bf16_t*)Xb, (const bf16_t*)W1t, b1s, b1d, fsb, fdb, N);
    gat_node_kernel<8><<<(N + 3) / 4, 256, 0, stream>>>(
        (const unsigned short*)fsb, (const unsigned short*)fdb, row_start, csr_src,
        attn1, x, ln1w, ln1b, nullptr, Xb, N);

    // --- layer 2: GEMM -> gat -> final f32 out
    gemm_mfma_dual_kernel<<<nwg, 512, 0, stream>>>(
        (const bf16_t*)Xb, (const bf16_t*)Wot, bos, bod, fsb, fdb, N);
    gat_node_kernel<1><<<(N + 3) / 4, 256, 0, stream>>>(
        (const unsigned short*)fsb, (const unsigned short*)fdb, row_start, csr_src,
        attno, nullptr, lnow, lnob, out, nullptr, N);
}

// Round 14
// 380.296 us; speedup vs baseline: 1.4454x; 1.0785x over previous
//
#include <hip/hip_runtime.h>
#include <hip/hip_bf16.h>
#include <math.h>

#define DIM 768

typedef __bf16 bf16_t;
typedef __attribute__((ext_vector_type(8))) __bf16 bf16x8;
typedef __attribute__((ext_vector_type(4))) float f32x4;

#define GLOAD_LDS16(g, l)                                                  \
    __builtin_amdgcn_global_load_lds(                                      \
        (const __attribute__((address_space(1))) void*)(g),                \
        (__attribute__((address_space(3))) void*)(l), 16, 0, 0)

__device__ __forceinline__ float bf2f(unsigned short u) {
    union { unsigned int i; float f; } x;
    x.i = ((unsigned int)u) << 16;
    return x.f;
}

// ---------------------------------------------------------------------------
// DPP-based group sum (VALU-only within 16 lanes; shfl beyond)
// ---------------------------------------------------------------------------
template <int CTRL>
__device__ __forceinline__ float dpp_add(float v) {
    int s = __builtin_amdgcn_update_dpp(0, __float_as_int(v), CTRL, 0xF, 0xF, true);
    return v + __int_as_float(s);
}

template <int G>
__device__ __forceinline__ float group_sum(float t) {
    t = dpp_add<0xB1>(t);                         // quad_perm xor1
    t = dpp_add<0x4E>(t);                         // quad_perm xor2
    t = dpp_add<0x141>(t);                        // row_half_mirror: 8-group
    if constexpr (G >= 16) t = dpp_add<0x140>(t); // row_mirror: 16-group
    if constexpr (G >= 32) t += __shfl_xor(t, 16, 64);
    if constexpr (G >= 64) t += __shfl_xor(t, 32, 64);
    return t;
}

// ---------------------------------------------------------------------------
// CSR build: hist -> parallel 3-stage scan -> scatter
// ---------------------------------------------------------------------------
__global__ __launch_bounds__(256) void hist_kernel(const int* __restrict__ dst,
                                                   int* __restrict__ deg, int E) {
    int e = blockIdx.x * 256 + threadIdx.x;
    if (e < E) atomicAdd(&deg[dst[e]], 1);
}

// stage 1: per-block (256) exclusive scan, emit block sums
__global__ __launch_bounds__(256) void scan_block_kernel(const int* __restrict__ deg,
                                                         int* __restrict__ excl,
                                                         int* __restrict__ bsum, int n) {
    __shared__ int sh[256];
    int b = blockIdx.x, tid = threadIdx.x, i = b * 256 + tid;
    int v = (i < n) ? deg[i] : 0;
    sh[tid] = v;
    __syncthreads();
    for (int off = 1; off < 256; off <<= 1) {
        int t = (tid >= off) ? sh[tid - off] : 0;
        __syncthreads();
        sh[tid] += t;
        __syncthreads();
    }
    if (i < n) excl[i] = sh[tid] - v;
    if (tid == 255) bsum[b] = sh[255];
}

// stage 2: single-block exclusive scan of block sums (nb <= 1024)
__global__ __launch_bounds__(1024) void scan_tops_kernel(int* __restrict__ bsum, int nb) {
    __shared__ int sh[1024];
    int tid = threadIdx.x;
    int v = (tid < nb) ? bsum[tid] : 0;
    sh[tid] = v;
    __syncthreads();
    for (int off = 1; off < 1024; off <<= 1) {
        int t = (tid >= off) ? sh[tid - off] : 0;
        __syncthreads();
        sh[tid] += t;
        __syncthreads();
    }
    if (tid < nb) bsum[tid] = sh[tid] - v;
}

// stage 3: add block offsets, emit row_start + cursor (+sentinel)
__global__ __launch_bounds__(256) void scan_fix_kernel(const int* __restrict__ excl,
                                                       const int* __restrict__ bsum,
                                                       int* __restrict__ row_start,
                                                       int* __restrict__ cursor,
                                                       int n, int E) {
    int i = blockIdx.x * 256 + threadIdx.x;
    if (i < n) {
        int v = excl[i] + bsum[blockIdx.x];
        row_start[i] = v;
        cursor[i] = v;
    }
    if (i == 0) row_start[n] = E;
}

__global__ __launch_bounds__(256) void scatter_kernel(const int* __restrict__ src,
                                                      const int* __restrict__ dst,
                                                      int* __restrict__ cursor,
                                                      int* __restrict__ csr_src, int E) {
    int e = blockIdx.x * 256 + threadIdx.x;
    if (e < E) {
        int p = atomicAdd(&cursor[dst[e]], 1);
        csr_src[p] = src[e];
    }
}

// ---------------------------------------------------------------------------
// fp32 -> bf16 elementwise convert (8 elems/thread)
// ---------------------------------------------------------------------------
__global__ __launch_bounds__(256) void conv_bf16_kernel(const float* __restrict__ in,
                                                        __hip_bfloat16* __restrict__ out,
                                                        int n8) {
    int i = blockIdx.x * 256 + threadIdx.x;
    if (i >= n8) return;
    const float4* p = reinterpret_cast<const float4*>(in + (size_t)i * 8);
    float4 a = p[0], b = p[1];
    __hip_bfloat16 v[8];
    v[0] = __float2bfloat16(a.x); v[1] = __float2bfloat16(a.y);
    v[2] = __float2bfloat16(a.z); v[3] = __float2bfloat16(a.w);
    v[4] = __float2bfloat16(b.x); v[5] = __float2bfloat16(b.y);
    v[6] = __float2bfloat16(b.z); v[7] = __float2bfloat16(b.w);
    *reinterpret_cast<uint4*>(out + (size_t)i * 8) = *reinterpret_cast<uint4*>(v);
}

// ---------------------------------------------------------------------------
// 4x batched W [768][768] f32 -> Wt [768][768] bf16 transpose (z = matrix id)
// ---------------------------------------------------------------------------
__global__ __launch_bounds__(256) void transpose4_bf16_kernel(
    const float* __restrict__ W0, const float* __restrict__ W1,
    const float* __restrict__ W2, const float* __restrict__ W3,
    __hip_bfloat16* __restrict__ Wt) {
    __shared__ float tile[32][33];
    int z = blockIdx.z;
    const float* W = (z == 0) ? W0 : (z == 1) ? W1 : (z == 2) ? W2 : W3;
    __hip_bfloat16* O = Wt + (size_t)z * DIM * DIM;
    int bk = blockIdx.x * 32, bn = blockIdx.y * 32;
    int tx = threadIdx.x & 31, ty = threadIdx.x >> 5;  // 32 x 8
#pragma unroll
    for (int r = ty; r < 32; r += 8)
        tile[r][tx] = W[(size_t)(bk + r) * DIM + bn + tx];
    __syncthreads();
#pragma unroll
    for (int r = ty; r < 32; r += 8)
        O[(size_t)(bn + r) * DIM + bk + tx] = __float2bfloat16(tile[tx][r]);
}

// ---------------------------------------------------------------------------
// Per-node GAT (defined BEFORE the GEMM: rule #19 regalloc-order shot at the
// 48-VGPR allocation). Round-6 loop structure: one wave per node, strided
// load12, 2-deep prefetch, max-free softmax, DPP reduce, __expf.
// Residual input is now bf16 (Xb still holds bf16(x) when gat<8> runs;
// each wave reads only its own row before overwriting it -> race-free).
// ---------------------------------------------------------------------------
__device__ __forceinline__ void load12(const unsigned short* __restrict__ p, float* v) {
    ushort4 a = *reinterpret_cast<const ushort4*>(p);
    ushort4 b = *reinterpret_cast<const ushort4*>(p + 4);
    ushort4 c = *reinterpret_cast<const ushort4*>(p + 8);
    v[0] = bf2f(a.x); v[1] = bf2f(a.y); v[2] = bf2f(a.z); v[3] = bf2f(a.w);
    v[4] = bf2f(b.x); v[5] = bf2f(b.y); v[6] = bf2f(b.z); v[7] = bf2f(b.w);
    v[8] = bf2f(c.x); v[9] = bf2f(c.y); v[10] = bf2f(c.z); v[11] = bf2f(c.w);
}

// one edge: logit -> DPP group reduce -> exp -> accumulate
#define PROCESS(FV)                                                         \
    do {                                                                    \
        float t = 0.f;                                                      \
        _Pragma("unroll") for (int j = 0; j < 12; ++j) {                    \
            float u = FV[j] + fdv[j];                                       \
            u = fmaxf(u, 0.2f * u);                                         \
            t = fmaf(u, av[j], t);                                          \
        }                                                                   \
        t = group_sum<G>(t);                                                \
        float ex = __expf(t);                                               \
        denom += ex;                                                        \
        _Pragma("unroll") for (int j = 0; j < 12; ++j)                      \
            agg[j] = fmaf(ex, FV[j], agg[j]);                               \
    } while (0)

template <int H>
__global__ __launch_bounds__(256) void gat_node_kernel(
    const unsigned short* __restrict__ fs, const unsigned short* __restrict__ fd,
    const int* __restrict__ row_start, const int* __restrict__ csr_src,
    const float* __restrict__ attn, const unsigned short* __restrict__ resid,
    const float* __restrict__ ln_w, const float* __restrict__ ln_b,
    float* __restrict__ outf, __hip_bfloat16* __restrict__ outb, int n_nodes) {
    constexpr int G = 64 / H;
    int wave = threadIdx.x >> 6;
    int lane = threadIdx.x & 63;
    int node = blockIdx.x * 4 + wave;
    if (node >= n_nodes) return;
    int d0 = lane * 12;

    float fdv[12], av[12], agg[12];
    load12(fd + (size_t)node * DIM + d0, fdv);
    {
        const float4* p = reinterpret_cast<const float4*>(attn + d0);
        float4 q0 = p[0], q1 = p[1], q2 = p[2];
        av[0] = q0.x; av[1] = q0.y; av[2] = q0.z; av[3] = q0.w;
        av[4] = q1.x; av[5] = q1.y; av[6] = q1.z; av[7] = q1.w;
        av[8] = q2.x; av[9] = q2.y; av[10] = q2.z; av[11] = q2.w;
    }
#pragma unroll
    for (int j = 0; j < 12; ++j) agg[j] = 0.f;

    int p0 = row_start[node], p1 = row_start[node + 1];
    int np = p1 - p0;
    float denom = 0.f;

    const unsigned short* fsl = fs + d0;
    const int* ip = csr_src + p0;

    float fvA[12], fvB[12];
    if (np > 0) load12(fsl + (size_t)ip[0] * DIM, fvA);
    if (np > 1) load12(fsl + (size_t)ip[1] * DIM, fvB);

    int i = 0;
    for (; i + 2 <= np; i += 2) {
        PROCESS(fvA);
        if (i + 2 < np) load12(fsl + (size_t)ip[i + 2] * DIM, fvA);
        PROCESS(fvB);
        if (i + 3 < np) load12(fsl + (size_t)ip[i + 3] * DIM, fvB);
    }
    if (i < np) PROCESS(fvA);

    float inv = (denom > 0.f) ? 1.0f / denom : 0.f;
    float vals[12];
#pragma unroll
    for (int j = 0; j < 12; ++j) {
        float v = agg[j] * inv;
        vals[j] = (v > 0.f) ? v : expm1f(v);
    }
    if (resid != nullptr) {
        float rv[12];
        load12(resid + (size_t)node * DIM + d0, rv);
#pragma unroll
        for (int j = 0; j < 12; ++j) vals[j] += rv[j];
    }
    float s1 = 0.f;
#pragma unroll
    for (int j = 0; j < 12; ++j) s1 += vals[j];
    s1 = group_sum<64>(s1);
    float mu = s1 * (1.0f / DIM);
    float s2 = 0.f;
#pragma unroll
    for (int j = 0; j < 12; ++j) {
        float dlt = vals[j] - mu;
        s2 = fmaf(dlt, dlt, s2);
    }
    s2 = group_sum<64>(s2);
    float rs = rsqrtf(s2 * (1.0f / DIM) + 1e-5f);

    float wv[12], bv[12];
    {
        const float4* p = reinterpret_cast<const float4*>(ln_w + d0);
        float4 q0 = p[0], q1 = p[1], q2 = p[2];
        wv[0] = q0.x; wv[1] = q0.y; wv[2] = q0.z; wv[3] = q0.w;
        wv[4] = q1.x; wv[5] = q1.y; wv[6] = q1.z; wv[7] = q1.w;
        wv[8] = q2.x; wv[9] = q2.y; wv[10] = q2.z; wv[11] = q2.w;
        const float4* pb = reinterpret_cast<const float4*>(ln_b + d0);
        float4 r0 = pb[0], r1 = pb[1], r2 = pb[2];
        bv[0] = r0.x; bv[1] = r0.y; bv[2] = r0.z; bv[3] = r0.w;
        bv[4] = r1.x; bv[5] = r1.y; bv[6] = r1.z; bv[7] = r1.w;
        bv[8] = r2.x; bv[9] = r2.y; bv[10] = r2.z; bv[11] = r2.w;
    }
    float o[12];
#pragma unroll
    for (int j = 0; j < 12; ++j)
        o[j] = (vals[j] - mu) * rs * wv[j] + bv[j];

    if (outf != nullptr) {
        float* op = outf + (size_t)node * DIM + d0;
#pragma unroll
        for (int qq = 0; qq < 3; ++qq) {
            float4 t4 = make_float4(o[qq * 4 + 0], o[qq * 4 + 1], o[qq * 4 + 2], o[qq * 4 + 3]);
            *reinterpret_cast<float4*>(op + qq * 4) = t4;
        }
    }
    if (outb != nullptr) {
        __hip_bfloat16 hb[12];
#pragma unroll
        for (int j = 0; j < 12; ++j) hb[j] = __float2bfloat16(o[j]);
        unsigned short* op = (unsigned short*)outb + (size_t)node * DIM + d0;
#pragma unroll
        for (int qq = 0; qq < 3; ++qq)
            *reinterpret_cast<ushort4*>(op + qq * 4) =
                *reinterpret_cast<ushort4*>(&hb[qq * 4]);
    }
}

// ---------------------------------------------------------------------------
// Dual bf16 MFMA GEMM: BM=256 x BN=128, BK=64, 512 threads (8 waves, 4x2),
// per-wave 64x64 output. XOR-swizzled LDS via pre-swizzled global source.
// 1D grid with bijective XCD-chunk swizzle, bn fastest. (unchanged, r12)
// ---------------------------------------------------------------------------
__global__ __launch_bounds__(512) void gemm_mfma_dual_kernel(
    const bf16_t* __restrict__ Xb,   // [M][768]
    const bf16_t* __restrict__ Wt,   // [1536][768]
    const float* __restrict__ b1, const float* __restrict__ b2,
    __hip_bfloat16* __restrict__ C1, __hip_bfloat16* __restrict__ C2, int M) {
    __shared__ __align__(16) bf16_t As[256 * 64];   // 32 KB
    __shared__ __align__(16) bf16_t Bs[128 * 64];   // 16 KB

    const int nwg = gridDim.x;
    const int o = blockIdx.x;
    const int q = nwg >> 3, r = nwg & 7;
    const int xcd = o & 7, jj = o >> 3;
    const int lin = (xcd < r ? xcd * (q + 1) : r * (q + 1) + (xcd - r) * q) + jj;
    const int bn = (lin % 12) * 128;
    const int bm = (lin / 12) * 256;

    const int tid = threadIdx.x;
    const int lane = tid & 63;
    const int w = tid >> 6;         // 0..7
    const int wrow = w >> 1;        // 0..3
    const int wcol = w & 1;         // 0..1

    f32x4 acc[4][4];
    {
        const float* bp = (bn < DIM) ? b1 : b2;
        int cb = (bn < DIM) ? bn : bn - DIM;
#pragma unroll
        for (int ni = 0; ni < 4; ++ni) {
            float bv = bp[cb + wcol * 64 + ni * 16 + (lane & 15)];
#pragma unroll
            for (int mi = 0; mi < 4; ++mi) acc[mi][ni] = f32x4{bv, bv, bv, bv};
        }
    }

    const int trow = tid >> 3;
    const int tcol = (tid & 7) * 8;

    for (int k0 = 0; k0 < DIM; k0 += 64) {
#pragma unroll
        for (int p = 0; p < 4; ++p) {
            int rr = p * 64 + trow;
            int col = tcol ^ ((rr & 7) << 3);
            int rg = bm + rr; rg = rg < M ? rg : M - 1;
            GLOAD_LDS16(Xb + (size_t)rg * DIM + k0 + col, &As[(p * 64 + w * 8) * 64]);
        }
#pragma unroll
        for (int p = 0; p < 2; ++p) {
            int rr = p * 64 + trow;
            int col = tcol ^ ((rr & 7) << 3);
            GLOAD_LDS16(Wt + (size_t)(bn + rr) * DIM + k0 + col, &Bs[(p * 64 + w * 8) * 64]);
        }
        __syncthreads();

#pragma unroll
        for (int kk = 0; kk < 2; ++kk) {
            bf16x8 af[4], bfr[4];
            int ke = kk * 32 + (lane >> 4) * 8;
#pragma unroll
            for (int mi = 0; mi < 4; ++mi) {
                int rr = wrow * 64 + mi * 16 + (lane & 15);
                af[mi] = *(const bf16x8*)&As[rr * 64 + (ke ^ ((rr & 7) << 3))];
            }
#pragma unroll
            for (int ni = 0; ni < 4; ++ni) {
                int rr = wcol * 64 + ni * 16 + (lane & 15);
                bfr[ni] = *(const bf16x8*)&Bs[rr * 64 + (ke ^ ((rr & 7) << 3))];
            }
#pragma unroll
            for (int mi = 0; mi < 4; ++mi)
#pragma unroll
                for (int ni = 0; ni < 4; ++ni)
                    acc[mi][ni] = __builtin_amdgcn_mfma_f32_16x16x32_bf16(
                        af[mi], bfr[ni], acc[mi][ni], 0, 0, 0);
        }
        __syncthreads();
    }

    __hip_bfloat16* C = (bn < DIM) ? C1 : C2;
    int cb = (bn < DIM) ? bn : bn - DIM;
#pragma unroll
    for (int mi = 0; mi < 4; ++mi) {
#pragma unroll
        for (int j = 0; j < 4; ++j) {
            int row = bm + wrow * 64 + mi * 16 + (lane >> 4) * 4 + j;
            if (row < M) {
#pragma unroll
                for (int ni = 0; ni < 4; ++ni) {
                    int col = cb + wcol * 64 + ni * 16 + (lane & 15);
                    C[(size_t)row * DIM + col] = __float2bfloat16(acc[mi][ni][j]);
                }
            }
        }
    }
}

// ---------------------------------------------------------------------------
extern "C" void kernel_launch(void* const* d_in, const int* in_sizes, int n_in,
                              void* d_out, int out_size, void* d_ws, size_t ws_size,
                              hipStream_t stream) {
    const float* x     = (const float*)d_in[0];
    const int*   src   = (const int*)d_in[1];
    const int*   dst   = (const int*)d_in[2];
    const float* W1s   = (const float*)d_in[3];
    const float* b1s   = (const float*)d_in[4];
    const float* W1d   = (const float*)d_in[5];
    const float* b1d   = (const float*)d_in[6];
    const float* attn1 = (const float*)d_in[7];
    const float* ln1w  = (const float*)d_in[8];
    const float* ln1b  = (const float*)d_in[9];
    const float* Wos   = (const float*)d_in[10];
    const float* bos   = (const float*)d_in[11];
    const float* Wod   = (const float*)d_in[12];
    const float* bod   = (const float*)d_in[13];
    const float* attno = (const float*)d_in[14];
    const float* lnow  = (const float*)d_in[15];
    const float* lnob  = (const float*)d_in[16];
    float* out = (float*)d_out;

    const int N = in_sizes[0] / DIM;   // 20000
    const int E = in_sizes[1];         // 320000

    __hip_bfloat16* fsb = (__hip_bfloat16*)d_ws;
    __hip_bfloat16* fdb = fsb + (size_t)N * DIM;
    __hip_bfloat16* Xb  = fdb + (size_t)N * DIM;
    __hip_bfloat16* W1t = Xb + (size_t)N * DIM;   // 4 contiguous 768x768 mats
    __hip_bfloat16* Wot = W1t + (size_t)2 * DIM * DIM;
    int* csr_src   = (int*)(Wot + (size_t)2 * DIM * DIM);
    int* row_start = csr_src + E;
    int* cursor    = row_start + (N + 1);
    int* deg       = cursor + N;
    int* excl      = deg + N;
    int* bsum      = excl + N;       // <= 128 entries

    const int nb = (N + 255) / 256;  // scan blocks (79)

    // --- CSR by dst (shared by both layers): hist -> 3-stage scan -> scatter
    hipMemsetAsync(deg, 0, (size_t)N * sizeof(int), stream);
    hist_kernel<<<(E + 255) / 256, 256, 0, stream>>>(dst, deg, E);
    scan_block_kernel<<<nb, 256, 0, stream>>>(deg, excl, bsum, N);
    scan_tops_kernel<<<1, 1024, 0, stream>>>(bsum, nb);
    scan_fix_kernel<<<nb, 256, 0, stream>>>(excl, bsum, row_start, cursor, N, E);
    scatter_kernel<<<(E + 255) / 256, 256, 0, stream>>>(src, dst, cursor, csr_src, E);

    // --- weight transposes, all 4 in one dispatch
    dim3 tg(DIM / 32, DIM / 32, 4);
    transpose4_bf16_kernel<<<tg, 256, 0, stream>>>(W1s, W1d, Wos, Wod, W1t);

    const int n8 = N * DIM / 8;
    const int mt = (N + 255) / 256;
    const int nwg = mt * 12;  // 1D swizzled grid (256x128 tiles)

    // --- layer 1: GEMM -> gat (bf16 resid from Xb; writes h into Xb)
    conv_bf16_kernel<<<(n8 + 255) / 256, 256, 0, stream>>>(x, Xb, n8);
    gemm_mfma_dual_kernel<<<nwg, 512, 0, stream>>>(
        (const bf16_t*)Xb, (const bf16_t*)W1t, b1s, b1d, fsb, fdb, N);
    gat_node_kernel<8><<<(N + 3) / 4, 256, 0, stream>>>(
        (const unsigned short*)fsb, (const unsigned short*)fdb, row_start, csr_src,
        attn1, (const unsigned short*)Xb, ln1w, ln1b, nullptr, Xb, N);

    // --- layer 2: GEMM -> gat -> final f32 out
    gemm_mfma_dual_kernel<<<nwg, 512, 0, stream>>>(
        (const bf16_t*)Xb, (const bf16_t*)Wot, bos, bod, fsb, fdb, N);
    gat_node_kernel<1><<<(N + 3) / 4, 256, 0, stream>>>(
        (const unsigned short*)fsb, (const unsigned short*)fdb, row_start, csr_src,
        attno, nullptr, lnow, lnob, out, nullptr, N);
}

// Round 15
// 371.918 us; speedup vs baseline: 1.4780x; 1.0225x over previous
//
#include <hip/hip_runtime.h>
#include <hip/hip_bf16.h>
#include <math.h>

#define DIM 768

typedef __bf16 bf16_t;
typedef __attribute__((ext_vector_type(8))) __bf16 bf16x8;
typedef __attribute__((ext_vector_type(4))) float f32x4;

#define GLOAD_LDS16(g, l)                                                  \
    __builtin_amdgcn_global_load_lds(                                      \
        (const __attribute__((address_space(1))) void*)(g),                \
        (__attribute__((address_space(3))) void*)(l), 16, 0, 0)

__device__ __forceinline__ float bf2f(unsigned short u) {
    union { unsigned int i; float f; } x;
    x.i = ((unsigned int)u) << 16;
    return x.f;
}

// ---------------------------------------------------------------------------
// DPP-based group sum (VALU-only within 16 lanes; shfl beyond)
// ---------------------------------------------------------------------------
template <int CTRL>
__device__ __forceinline__ float dpp_add(float v) {
    int s = __builtin_amdgcn_update_dpp(0, __float_as_int(v), CTRL, 0xF, 0xF, true);
    return v + __int_as_float(s);
}

template <int G>
__device__ __forceinline__ float group_sum(float t) {
    t = dpp_add<0xB1>(t);                         // quad_perm xor1
    t = dpp_add<0x4E>(t);                         // quad_perm xor2
    t = dpp_add<0x141>(t);                        // row_half_mirror: 8-group
    if constexpr (G >= 16) t = dpp_add<0x140>(t); // row_mirror: 16-group
    if constexpr (G >= 32) t += __shfl_xor(t, 16, 64);
    if constexpr (G >= 64) t += __shfl_xor(t, 32, 64);
    return t;
}

// ---------------------------------------------------------------------------
// CSR build: hist -> parallel 3-stage scan -> scatter
// ---------------------------------------------------------------------------
__global__ __launch_bounds__(256) void hist_kernel(const int* __restrict__ dst,
                                                   int* __restrict__ deg, int E) {
    int e = blockIdx.x * 256 + threadIdx.x;
    if (e < E) atomicAdd(&deg[dst[e]], 1);
}

__global__ __launch_bounds__(256) void scan_block_kernel(const int* __restrict__ deg,
                                                         int* __restrict__ excl,
                                                         int* __restrict__ bsum, int n) {
    __shared__ int sh[256];
    int b = blockIdx.x, tid = threadIdx.x, i = b * 256 + tid;
    int v = (i < n) ? deg[i] : 0;
    sh[tid] = v;
    __syncthreads();
    for (int off = 1; off < 256; off <<= 1) {
        int t = (tid >= off) ? sh[tid - off] : 0;
        __syncthreads();
        sh[tid] += t;
        __syncthreads();
    }
    if (i < n) excl[i] = sh[tid] - v;
    if (tid == 255) bsum[b] = sh[255];
}

__global__ __launch_bounds__(1024) void scan_tops_kernel(int* __restrict__ bsum, int nb) {
    __shared__ int sh[1024];
    int tid = threadIdx.x;
    int v = (tid < nb) ? bsum[tid] : 0;
    sh[tid] = v;
    __syncthreads();
    for (int off = 1; off < 1024; off <<= 1) {
        int t = (tid >= off) ? sh[tid - off] : 0;
        __syncthreads();
        sh[tid] += t;
        __syncthreads();
    }
    if (tid < nb) bsum[tid] = sh[tid] - v;
}

__global__ __launch_bounds__(256) void scan_fix_kernel(const int* __restrict__ excl,
                                                       const int* __restrict__ bsum,
                                                       int* __restrict__ row_start,
                                                       int* __restrict__ cursor,
                                                       int n, int E) {
    int i = blockIdx.x * 256 + threadIdx.x;
    if (i < n) {
        int v = excl[i] + bsum[blockIdx.x];
        row_start[i] = v;
        cursor[i] = v;
    }
    if (i == 0) row_start[n] = E;
}

__global__ __launch_bounds__(256) void scatter_kernel(const int* __restrict__ src,
                                                      const int* __restrict__ dst,
                                                      int* __restrict__ cursor,
                                                      int* __restrict__ csr_src, int E) {
    int e = blockIdx.x * 256 + threadIdx.x;
    if (e < E) {
        int p = atomicAdd(&cursor[dst[e]], 1);
        csr_src[p] = src[e];
    }
}

// ---------------------------------------------------------------------------
// fp32 -> bf16 elementwise convert (8 elems/thread)
// ---------------------------------------------------------------------------
__global__ __launch_bounds__(256) void conv_bf16_kernel(const float* __restrict__ in,
                                                        __hip_bfloat16* __restrict__ out,
                                                        int n8) {
    int i = blockIdx.x * 256 + threadIdx.x;
    if (i >= n8) return;
    const float4* p = reinterpret_cast<const float4*>(in + (size_t)i * 8);
    float4 a = p[0], b = p[1];
    __hip_bfloat16 v[8];
    v[0] = __float2bfloat16(a.x); v[1] = __float2bfloat16(a.y);
    v[2] = __float2bfloat16(a.z); v[3] = __float2bfloat16(a.w);
    v[4] = __float2bfloat16(b.x); v[5] = __float2bfloat16(b.y);
    v[6] = __float2bfloat16(b.z); v[7] = __float2bfloat16(b.w);
    *reinterpret_cast<uint4*>(out + (size_t)i * 8) = *reinterpret_cast<uint4*>(v);
}

// ---------------------------------------------------------------------------
// 4x batched W [768][768] f32 -> Wt [768][768] bf16 transpose (z = matrix id)
// ---------------------------------------------------------------------------
__global__ __launch_bounds__(256) void transpose4_bf16_kernel(
    const float* __restrict__ W0, const float* __restrict__ W1,
    const float* __restrict__ W2, const float* __restrict__ W3,
    __hip_bfloat16* __restrict__ Wt) {
    __shared__ float tile[32][33];
    int z = blockIdx.z;
    const float* W = (z == 0) ? W0 : (z == 1) ? W1 : (z == 2) ? W2 : W3;
    __hip_bfloat16* O = Wt + (size_t)z * DIM * DIM;
    int bk = blockIdx.x * 32, bn = blockIdx.y * 32;
    int tx = threadIdx.x & 31, ty = threadIdx.x >> 5;  // 32 x 8
#pragma unroll
    for (int r = ty; r < 32; r += 8)
        tile[r][tx] = W[(size_t)(bk + r) * DIM + bn + tx];
    __syncthreads();
#pragma unroll
    for (int r = ty; r < 32; r += 8)
        O[(size_t)(bn + r) * DIM + bk + tx] = __float2bfloat16(tile[tx][r]);
}

// ---------------------------------------------------------------------------
// Per-node GAT: round-6 loop structure. VALU cuts this round:
//  (1) LeakyReLU-via-abs: max(u,.2u) == .6u+.4|u|  ->  two accumulators,
//      |u| free as VOP3 modifier; combine folded with log2e into exp2.
//  (2) ELU via __expf(v)-1 instead of libm expm1f (epilogue).
// ---------------------------------------------------------------------------
__device__ __forceinline__ void load12(const unsigned short* __restrict__ p, float* v) {
    ushort4 a = *reinterpret_cast<const ushort4*>(p);
    ushort4 b = *reinterpret_cast<const ushort4*>(p + 4);
    ushort4 c = *reinterpret_cast<const ushort4*>(p + 8);
    v[0] = bf2f(a.x); v[1] = bf2f(a.y); v[2] = bf2f(a.z); v[3] = bf2f(a.w);
    v[4] = bf2f(b.x); v[5] = bf2f(b.y); v[6] = bf2f(b.z); v[7] = bf2f(b.w);
    v[8] = bf2f(c.x); v[9] = bf2f(c.y); v[10] = bf2f(c.z); v[11] = bf2f(c.w);
}

// one edge: logit (abs-trick) -> DPP group reduce -> exp2 -> accumulate
// C6 = 0.6*log2e, C4 = 0.4*log2e folded so exp(t) == exp2(C6*t1 + C4*t2)
#define PROCESS(FV)                                                         \
    do {                                                                    \
        float t1 = 0.f, t2 = 0.f;                                           \
        _Pragma("unroll") for (int j = 0; j < 12; ++j) {                    \
            float u = FV[j] + fdv[j];                                       \
            t1 = fmaf(u, av[j], t1);                                        \
            t2 = fmaf(__builtin_fabsf(u), av[j], t2);                       \
        }                                                                   \
        float t = fmaf(0.86561702f, t1, 0.57707801f * t2);                  \
        t = group_sum<G>(t);                                                \
        float ex = exp2f(t);                                                \
        denom += ex;                                                        \
        _Pragma("unroll") for (int j = 0; j < 12; ++j)                      \
            agg[j] = fmaf(ex, FV[j], agg[j]);                               \
    } while (0)

template <int H>
__global__ __launch_bounds__(256) void gat_node_kernel(
    const unsigned short* __restrict__ fs, const unsigned short* __restrict__ fd,
    const int* __restrict__ row_start, const int* __restrict__ csr_src,
    const float* __restrict__ attn, const unsigned short* __restrict__ resid,
    const float* __restrict__ ln_w, const float* __restrict__ ln_b,
    float* __restrict__ outf, __hip_bfloat16* __restrict__ outb, int n_nodes) {
    constexpr int G = 64 / H;
    int wave = threadIdx.x >> 6;
    int lane = threadIdx.x & 63;
    int node = blockIdx.x * 4 + wave;
    if (node >= n_nodes) return;
    int d0 = lane * 12;

    float fdv[12], av[12], agg[12];
    load12(fd + (size_t)node * DIM + d0, fdv);
    {
        const float4* p = reinterpret_cast<const float4*>(attn + d0);
        float4 q0 = p[0], q1 = p[1], q2 = p[2];
        av[0] = q0.x; av[1] = q0.y; av[2] = q0.z; av[3] = q0.w;
        av[4] = q1.x; av[5] = q1.y; av[6] = q1.z; av[7] = q1.w;
        av[8] = q2.x; av[9] = q2.y; av[10] = q2.z; av[11] = q2.w;
    }
#pragma unroll
    for (int j = 0; j < 12; ++j) agg[j] = 0.f;

    int p0 = row_start[node], p1 = row_start[node + 1];
    int np = p1 - p0;
    float denom = 0.f;

    const unsigned short* fsl = fs + d0;
    const int* ip = csr_src + p0;

    float fvA[12], fvB[12];
    if (np > 0) load12(fsl + (size_t)ip[0] * DIM, fvA);
    if (np > 1) load12(fsl + (size_t)ip[1] * DIM, fvB);

    int i = 0;
    for (; i + 2 <= np; i += 2) {
        PROCESS(fvA);
        if (i + 2 < np) load12(fsl + (size_t)ip[i + 2] * DIM, fvA);
        PROCESS(fvB);
        if (i + 3 < np) load12(fsl + (size_t)ip[i + 3] * DIM, fvB);
    }
    if (i < np) PROCESS(fvA);

    float inv = (denom > 0.f) ? 1.0f / denom : 0.f;
    float vals[12];
#pragma unroll
    for (int j = 0; j < 12; ++j) {
        float v = agg[j] * inv;
        vals[j] = (v > 0.f) ? v : (__expf(v) - 1.0f);
    }
    if (resid != nullptr) {
        float rv[12];
        load12(resid + (size_t)node * DIM + d0, rv);
#pragma unroll
        for (int j = 0; j < 12; ++j) vals[j] += rv[j];
    }
    float s1 = 0.f;
#pragma unroll
    for (int j = 0; j < 12; ++j) s1 += vals[j];
    s1 = group_sum<64>(s1);
    float mu = s1 * (1.0f / DIM);
    float s2 = 0.f;
#pragma unroll
    for (int j = 0; j < 12; ++j) {
        float dlt = vals[j] - mu;
        s2 = fmaf(dlt, dlt, s2);
    }
    s2 = group_sum<64>(s2);
    float rs = rsqrtf(s2 * (1.0f / DIM) + 1e-5f);

    float wv[12], bv[12];
    {
        const float4* p = reinterpret_cast<const float4*>(ln_w + d0);
        float4 q0 = p[0], q1 = p[1], q2 = p[2];
        wv[0] = q0.x; wv[1] = q0.y; wv[2] = q0.z; wv[3] = q0.w;
        wv[4] = q1.x; wv[5] = q1.y; wv[6] = q1.z; wv[7] = q1.w;
        wv[8] = q2.x; wv[9] = q2.y; wv[10] = q2.z; wv[11] = q2.w;
        const float4* pb = reinterpret_cast<const float4*>(ln_b + d0);
        float4 r0 = pb[0], r1 = pb[1], r2 = pb[2];
        bv[0] = r0.x; bv[1] = r0.y; bv[2] = r0.z; bv[3] = r0.w;
        bv[4] = r1.x; bv[5] = r1.y; bv[6] = r1.z; bv[7] = r1.w;
        bv[8] = r2.x; bv[9] = r2.y; bv[10] = r2.z; bv[11] = r2.w;
    }
    float o[12];
#pragma unroll
    for (int j = 0; j < 12; ++j)
        o[j] = (vals[j] - mu) * rs * wv[j] + bv[j];

    if (outf != nullptr) {
        float* op = outf + (size_t)node * DIM + d0;
#pragma unroll
        for (int qq = 0; qq < 3; ++qq) {
            float4 t4 = make_float4(o[qq * 4 + 0], o[qq * 4 + 1], o[qq * 4 + 2], o[qq * 4 + 3]);
            *reinterpret_cast<float4*>(op + qq * 4) = t4;
        }
    }
    if (outb != nullptr) {
        __hip_bfloat16 hb[12];
#pragma unroll
        for (int j = 0; j < 12; ++j) hb[j] = __float2bfloat16(o[j]);
        unsigned short* op = (unsigned short*)outb + (size_t)node * DIM + d0;
#pragma unroll
        for (int qq = 0; qq < 3; ++qq)
            *reinterpret_cast<ushort4*>(op + qq * 4) =
                *reinterpret_cast<ushort4*>(&hb[qq * 4]);
    }
}

// ---------------------------------------------------------------------------
// Dual bf16 MFMA GEMM: BM=256 x BN=128, BK=64, 512 threads (8 waves, 4x2),
// per-wave 64x64 output. XOR-swizzled LDS via pre-swizzled global source.
// 1D grid with bijective XCD-chunk swizzle, bn fastest. (unchanged, r12)
// ---------------------------------------------------------------------------
__global__ __launch_bounds__(512) void gemm_mfma_dual_kernel(
    const bf16_t* __restrict__ Xb,   // [M][768]
    const bf16_t* __restrict__ Wt,   // [1536][768]
    const float* __restrict__ b1, const float* __restrict__ b2,
    __hip_bfloat16* __restrict__ C1, __hip_bfloat16* __restrict__ C2, int M) {
    __shared__ __align__(16) bf16_t As[256 * 64];   // 32 KB
    __shared__ __align__(16) bf16_t Bs[128 * 64];   // 16 KB

    const int nwg = gridDim.x;
    const int o = blockIdx.x;
    const int q = nwg >> 3, r = nwg & 7;
    const int xcd = o & 7, jj = o >> 3;
    const int lin = (xcd < r ? xcd * (q + 1) : r * (q + 1) + (xcd - r) * q) + jj;
    const int bn = (lin % 12) * 128;
    const int bm = (lin / 12) * 256;

    const int tid = threadIdx.x;
    const int lane = tid & 63;
    const int w = tid >> 6;         // 0..7
    const int wrow = w >> 1;        // 0..3
    const int wcol = w & 1;         // 0..1

    f32x4 acc[4][4];
    {
        const float* bp = (bn < DIM) ? b1 : b2;
        int cb = (bn < DIM) ? bn : bn - DIM;
#pragma unroll
        for (int ni = 0; ni < 4; ++ni) {
            float bv = bp[cb + wcol * 64 + ni * 16 + (lane & 15)];
#pragma unroll
            for (int mi = 0; mi < 4; ++mi) acc[mi][ni] = f32x4{bv, bv, bv, bv};
        }
    }

    const int trow = tid >> 3;
    const int tcol = (tid & 7) * 8;

    for (int k0 = 0; k0 < DIM; k0 += 64) {
#pragma unroll
        for (int p = 0; p < 4; ++p) {
            int rr = p * 64 + trow;
            int col = tcol ^ ((rr & 7) << 3);
            int rg = bm + rr; rg = rg < M ? rg : M - 1;
            GLOAD_LDS16(Xb + (size_t)rg * DIM + k0 + col, &As[(p * 64 + w * 8) * 64]);
        }
#pragma unroll
        for (int p = 0; p < 2; ++p) {
            int rr = p * 64 + trow;
            int col = tcol ^ ((rr & 7) << 3);
            GLOAD_LDS16(Wt + (size_t)(bn + rr) * DIM + k0 + col, &Bs[(p * 64 + w * 8) * 64]);
        }
        __syncthreads();

#pragma unroll
        for (int kk = 0; kk < 2; ++kk) {
            bf16x8 af[4], bfr[4];
            int ke = kk * 32 + (lane >> 4) * 8;
#pragma unroll
            for (int mi = 0; mi < 4; ++mi) {
                int rr = wrow * 64 + mi * 16 + (lane & 15);
                af[mi] = *(const bf16x8*)&As[rr * 64 + (ke ^ ((rr & 7) << 3))];
            }
#pragma unroll
            for (int ni = 0; ni < 4; ++ni) {
                int rr = wcol * 64 + ni * 16 + (lane & 15);
                bfr[ni] = *(const bf16x8*)&Bs[rr * 64 + (ke ^ ((rr & 7) << 3))];
            }
#pragma unroll
            for (int mi = 0; mi < 4; ++mi)
#pragma unroll
                for (int ni = 0; ni < 4; ++ni)
                    acc[mi][ni] = __builtin_amdgcn_mfma_f32_16x16x32_bf16(
                        af[mi], bfr[ni], acc[mi][ni], 0, 0, 0);
        }
        __syncthreads();
    }

    __hip_bfloat16* C = (bn < DIM) ? C1 : C2;
    int cb = (bn < DIM) ? bn : bn - DIM;
#pragma unroll
    for (int mi = 0; mi < 4; ++mi) {
#pragma unroll
        for (int j = 0; j < 4; ++j) {
            int row = bm + wrow * 64 + mi * 16 + (lane >> 4) * 4 + j;
            if (row < M) {
#pragma unroll
                for (int ni = 0; ni < 4; ++ni) {
                    int col = cb + wcol * 64 + ni * 16 + (lane & 15);
                    C[(size_t)row * DIM + col] = __float2bfloat16(acc[mi][ni][j]);
                }
            }
        }
    }
}

// ---------------------------------------------------------------------------
extern "C" void kernel_launch(void* const* d_in, const int* in_sizes, int n_in,
                              void* d_out, int out_size, void* d_ws, size_t ws_size,
                              hipStream_t stream) {
    const float* x     = (const float*)d_in[0];
    const int*   src   = (const int*)d_in[1];
    const int*   dst   = (const int*)d_in[2];
    const float* W1s   = (const float*)d_in[3];
    const float* b1s   = (const float*)d_in[4];
    const float* W1d   = (const float*)d_in[5];
    const float* b1d   = (const float*)d_in[6];
    const float* attn1 = (const float*)d_in[7];
    const float* ln1w  = (const float*)d_in[8];
    const float* ln1b  = (const float*)d_in[9];
    const float* Wos   = (const float*)d_in[10];
    const float* bos   = (const float*)d_in[11];
    const float* Wod   = (const float*)d_in[12];
    const float* bod   = (const float*)d_in[13];
    const float* attno = (const float*)d_in[14];
    const float* lnow  = (const float*)d_in[15];
    const float* lnob  = (const float*)d_in[16];
    float* out = (float*)d_out;

    const int N = in_sizes[0] / DIM;   // 20000
    const int E = in_sizes[1];         // 320000

    __hip_bfloat16* fsb = (__hip_bfloat16*)d_ws;
    __hip_bfloat16* fdb = fsb + (size_t)N * DIM;
    __hip_bfloat16* Xb  = fdb + (size_t)N * DIM;
    __hip_bfloat16* W1t = Xb + (size_t)N * DIM;   // 4 contiguous 768x768 mats
    __hip_bfloat16* Wot = W1t + (size_t)2 * DIM * DIM;
    int* csr_src   = (int*)(Wot + (size_t)2 * DIM * DIM);
    int* row_start = csr_src + E;
    int* cursor    = row_start + (N + 1);
    int* deg       = cursor + N;
    int* excl      = deg + N;
    int* bsum      = excl + N;       // <= 128 entries

    const int nb = (N + 255) / 256;  // scan blocks (79)

    // --- CSR by dst (shared by both layers): hist -> 3-stage scan -> scatter
    hipMemsetAsync(deg, 0, (size_t)N * sizeof(int), stream);
    hist_kernel<<<(E + 255) / 256, 256, 0, stream>>>(dst, deg, E);
    scan_block_kernel<<<nb, 256, 0, stream>>>(deg, excl, bsum, N);
    scan_tops_kernel<<<1, 1024, 0, stream>>>(bsum, nb);
    scan_fix_kernel<<<nb, 256, 0, stream>>>(excl, bsum, row_start, cursor, N, E);
    scatter_kernel<<<(E + 255) / 256, 256, 0, stream>>>(src, dst, cursor, csr_src, E);

    // --- weight transposes, all 4 in one dispatch
    dim3 tg(DIM / 32, DIM / 32, 4);
    transpose4_bf16_kernel<<<tg, 256, 0, stream>>>(W1s, W1d, Wos, Wod, W1t);

    const int n8 = N * DIM / 8;
    const int mt = (N + 255) / 256;
    const int nwg = mt * 12;  // 1D swizzled grid (256x128 tiles)

    // --- layer 1: GEMM -> gat (bf16 resid from Xb; writes h into Xb)
    conv_bf16_kernel<<<(n8 + 255) / 256, 256, 0, stream>>>(x, Xb, n8);
    gemm_mfma_dual_kernel<<<nwg, 512, 0, stream>>>(
        (const bf16_t*)Xb, (const bf16_t*)W1t, b1s, b1d, fsb, fdb, N);
    gat_node_kernel<8><<<(N + 3) / 4, 256, 0, stream>>>(
        (const unsigned short*)fsb, (const unsigned short*)fdb, row_start, csr_src,
        attn1, (const unsigned short*)Xb, ln1w, ln1b, nullptr, Xb, N);

    // --- layer 2: GEMM -> gat -> final f32 out
    gemm_mfma_dual_kernel<<<nwg, 512, 0, stream>>>(
        (const bf16_t*)Xb, (const bf16_t*)Wot, bos, bod, fsb, fdb, N);
    gat_node_kernel<1><<<(N + 3) / 4, 256, 0, stream>>>(
        (const unsigned short*)fsb, (const unsigned short*)fdb, row_start, csr_src,
        attno, nullptr, lnow, lnob, out, nullptr, N);
}

// Round 16
// 363.464 us; speedup vs baseline: 1.5124x; 1.0233x over previous
//
#include <hip/hip_runtime.h>
#include <hip/hip_bf16.h>
#include <hip/hip_fp8.h>
#include <math.h>

#define DIM 768

typedef __bf16 bf16_t;
typedef __attribute__((ext_vector_type(8))) __bf16 bf16x8;
typedef __attribute__((ext_vector_type(4))) float f32x4;
typedef __attribute__((ext_vector_type(2))) float f32x2v;

#define GLOAD_LDS16(g, l)                                                  \
    __builtin_amdgcn_global_load_lds(                                      \
        (const __attribute__((address_space(1))) void*)(g),                \
        (__attribute__((address_space(3))) void*)(l), 16, 0, 0)

__device__ __forceinline__ float bf2f(unsigned short u) {
    union { unsigned int i; float f; } x;
    x.i = ((unsigned int)u) << 16;
    return x.f;
}

// ---------------------------------------------------------------------------
// DPP-based group sum (VALU-only within 16 lanes; shfl beyond)
// ---------------------------------------------------------------------------
template <int CTRL>
__device__ __forceinline__ float dpp_add(float v) {
    int s = __builtin_amdgcn_update_dpp(0, __float_as_int(v), CTRL, 0xF, 0xF, true);
    return v + __int_as_float(s);
}

template <int G>
__device__ __forceinline__ float group_sum(float t) {
    t = dpp_add<0xB1>(t);                         // quad_perm xor1
    t = dpp_add<0x4E>(t);                         // quad_perm xor2
    t = dpp_add<0x141>(t);                        // row_half_mirror: 8-group
    if constexpr (G >= 16) t = dpp_add<0x140>(t); // row_mirror: 16-group
    if constexpr (G >= 32) t += __shfl_xor(t, 16, 64);
    if constexpr (G >= 64) t += __shfl_xor(t, 32, 64);
    return t;
}

// ---------------------------------------------------------------------------
// CSR build: hist -> parallel 3-stage scan -> scatter
// ---------------------------------------------------------------------------
__global__ __launch_bounds__(256) void hist_kernel(const int* __restrict__ dst,
                                                   int* __restrict__ deg, int E) {
    int e = blockIdx.x * 256 + threadIdx.x;
    if (e < E) atomicAdd(&deg[dst[e]], 1);
}

__global__ __launch_bounds__(256) void scan_block_kernel(const int* __restrict__ deg,
                                                         int* __restrict__ excl,
                                                         int* __restrict__ bsum, int n) {
    __shared__ int sh[256];
    int b = blockIdx.x, tid = threadIdx.x, i = b * 256 + tid;
    int v = (i < n) ? deg[i] : 0;
    sh[tid] = v;
    __syncthreads();
    for (int off = 1; off < 256; off <<= 1) {
        int t = (tid >= off) ? sh[tid - off] : 0;
        __syncthreads();
        sh[tid] += t;
        __syncthreads();
    }
    if (i < n) excl[i] = sh[tid] - v;
    if (tid == 255) bsum[b] = sh[255];
}

__global__ __launch_bounds__(1024) void scan_tops_kernel(int* __restrict__ bsum, int nb) {
    __shared__ int sh[1024];
    int tid = threadIdx.x;
    int v = (tid < nb) ? bsum[tid] : 0;
    sh[tid] = v;
    __syncthreads();
    for (int off = 1; off < 1024; off <<= 1) {
        int t = (tid >= off) ? sh[tid - off] : 0;
        __syncthreads();
        sh[tid] += t;
        __syncthreads();
    }
    if (tid < nb) bsum[tid] = sh[tid] - v;
}

__global__ __launch_bounds__(256) void scan_fix_kernel(const int* __restrict__ excl,
                                                       const int* __restrict__ bsum,
                                                       int* __restrict__ row_start,
                                                       int* __restrict__ cursor,
                                                       int n, int E) {
    int i = blockIdx.x * 256 + threadIdx.x;
    if (i < n) {
        int v = excl[i] + bsum[blockIdx.x];
        row_start[i] = v;
        cursor[i] = v;
    }
    if (i == 0) row_start[n] = E;
}

__global__ __launch_bounds__(256) void scatter_kernel(const int* __restrict__ src,
                                                      const int* __restrict__ dst,
                                                      int* __restrict__ cursor,
                                                      int* __restrict__ csr_src, int E) {
    int e = blockIdx.x * 256 + threadIdx.x;
    if (e < E) {
        int p = atomicAdd(&cursor[dst[e]], 1);
        csr_src[p] = src[e];
    }
}

// ---------------------------------------------------------------------------
// fp32 -> bf16 elementwise convert (8 elems/thread)
// ---------------------------------------------------------------------------
__global__ __launch_bounds__(256) void conv_bf16_kernel(const float* __restrict__ in,
                                                        __hip_bfloat16* __restrict__ out,
                                                        int n8) {
    int i = blockIdx.x * 256 + threadIdx.x;
    if (i >= n8) return;
    const float4* p = reinterpret_cast<const float4*>(in + (size_t)i * 8);
    float4 a = p[0], b = p[1];
    __hip_bfloat16 v[8];
    v[0] = __float2bfloat16(a.x); v[1] = __float2bfloat16(a.y);
    v[2] = __float2bfloat16(a.z); v[3] = __float2bfloat16(a.w);
    v[4] = __float2bfloat16(b.x); v[5] = __float2bfloat16(b.y);
    v[6] = __float2bfloat16(b.z); v[7] = __float2bfloat16(b.w);
    *reinterpret_cast<uint4*>(out + (size_t)i * 8) = *reinterpret_cast<uint4*>(v);
}

// ---------------------------------------------------------------------------
// 4x batched W [768][768] f32 -> Wt [768][768] bf16 transpose (z = matrix id)
// ---------------------------------------------------------------------------
__global__ __launch_bounds__(256) void transpose4_bf16_kernel(
    const float* __restrict__ W0, const float* __restrict__ W1,
    const float* __restrict__ W2, const float* __restrict__ W3,
    __hip_bfloat16* __restrict__ Wt) {
    __shared__ float tile[32][33];
    int z = blockIdx.z;
    const float* W = (z == 0) ? W0 : (z == 1) ? W1 : (z == 2) ? W2 : W3;
    __hip_bfloat16* O = Wt + (size_t)z * DIM * DIM;
    int bk = blockIdx.x * 32, bn = blockIdx.y * 32;
    int tx = threadIdx.x & 31, ty = threadIdx.x >> 5;  // 32 x 8
#pragma unroll
    for (int r = ty; r < 32; r += 8)
        tile[r][tx] = W[(size_t)(bk + r) * DIM + bn + tx];
    __syncthreads();
#pragma unroll
    for (int r = ty; r < 32; r += 8)
        O[(size_t)(bn + r) * DIM + bk + tx] = __float2bfloat16(tile[tx][r]);
}

// ---------------------------------------------------------------------------
// fp8 helpers (OCP e4m3, gfx950-native)
// ---------------------------------------------------------------------------
__device__ __forceinline__ unsigned char f32_to_fp8(float f) {
    __hip_fp8_e4m3 q(f);
    return (unsigned char)q.__x;
}

__device__ __forceinline__ void load12f8(const unsigned char* __restrict__ p, float* v) {
    const unsigned int* dp = reinterpret_cast<const unsigned int*>(p);
    unsigned int d0 = dp[0], d1 = dp[1], d2 = dp[2];
#if __has_builtin(__builtin_amdgcn_cvt_pk_f32_fp8)
    f32x2v a0 = __builtin_amdgcn_cvt_pk_f32_fp8(d0, false);
    f32x2v a1 = __builtin_amdgcn_cvt_pk_f32_fp8(d0, true);
    f32x2v b0 = __builtin_amdgcn_cvt_pk_f32_fp8(d1, false);
    f32x2v b1 = __builtin_amdgcn_cvt_pk_f32_fp8(d1, true);
    f32x2v c0 = __builtin_amdgcn_cvt_pk_f32_fp8(d2, false);
    f32x2v c1 = __builtin_amdgcn_cvt_pk_f32_fp8(d2, true);
    v[0] = a0.x; v[1] = a0.y; v[2] = a1.x; v[3] = a1.y;
    v[4] = b0.x; v[5] = b0.y; v[6] = b1.x; v[7] = b1.y;
    v[8] = c0.x; v[9] = c0.y; v[10] = c1.x; v[11] = c1.y;
#else
    unsigned int d[3] = {d0, d1, d2};
#pragma unroll
    for (int k = 0; k < 12; ++k) {
        __hip_fp8_e4m3 t;
        t.__x = (d[k >> 2] >> ((k & 3) * 8)) & 0xff;
        v[k] = (float)t;
    }
#endif
}

// ---------------------------------------------------------------------------
// Per-node GAT. FS8: fs table is fp8 e4m3 (halved gather traffic); else bf16.
// Round-6 loop structure + abs-trick logit + exp2 + cheap ELU.
// ---------------------------------------------------------------------------
__device__ __forceinline__ void load12(const unsigned short* __restrict__ p, float* v) {
    ushort4 a = *reinterpret_cast<const ushort4*>(p);
    ushort4 b = *reinterpret_cast<const ushort4*>(p + 4);
    ushort4 c = *reinterpret_cast<const ushort4*>(p + 8);
    v[0] = bf2f(a.x); v[1] = bf2f(a.y); v[2] = bf2f(a.z); v[3] = bf2f(a.w);
    v[4] = bf2f(b.x); v[5] = bf2f(b.y); v[6] = bf2f(b.z); v[7] = bf2f(b.w);
    v[8] = bf2f(c.x); v[9] = bf2f(c.y); v[10] = bf2f(c.z); v[11] = bf2f(c.w);
}

#define LOADFV(S, BUF)                                                      \
    do {                                                                    \
        if constexpr (FS8) load12f8(fs8l + (size_t)(S) * DIM, BUF);         \
        else load12(fs16l + (size_t)(S) * DIM, BUF);                        \
    } while (0)

// one edge: logit (abs-trick) -> DPP group reduce -> exp2 -> accumulate
#define PROCESS(FV)                                                         \
    do {                                                                    \
        float t1 = 0.f, t2 = 0.f;                                           \
        _Pragma("unroll") for (int j = 0; j < 12; ++j) {                    \
            float u = FV[j] + fdv[j];                                       \
            t1 = fmaf(u, av[j], t1);                                        \
            t2 = fmaf(__builtin_fabsf(u), av[j], t2);                       \
        }                                                                   \
        float t = fmaf(0.86561702f, t1, 0.57707801f * t2);                  \
        t = group_sum<G>(t);                                                \
        float ex = exp2f(t);                                                \
        denom += ex;                                                        \
        _Pragma("unroll") for (int j = 0; j < 12; ++j)                      \
            agg[j] = fmaf(ex, FV[j], agg[j]);                               \
    } while (0)

template <int H, bool FS8>
__global__ __launch_bounds__(256) void gat_node_kernel(
    const void* __restrict__ fs, const unsigned short* __restrict__ fd,
    const int* __restrict__ row_start, const int* __restrict__ csr_src,
    const float* __restrict__ attn, const unsigned short* __restrict__ resid,
    const float* __restrict__ ln_w, const float* __restrict__ ln_b,
    float* __restrict__ outf, __hip_bfloat16* __restrict__ outb, int n_nodes) {
    constexpr int G = 64 / H;
    int wave = threadIdx.x >> 6;
    int lane = threadIdx.x & 63;
    int node = blockIdx.x * 4 + wave;
    if (node >= n_nodes) return;
    int d0 = lane * 12;

    float fdv[12], av[12], agg[12];
    load12(fd + (size_t)node * DIM + d0, fdv);
    {
        const float4* p = reinterpret_cast<const float4*>(attn + d0);
        float4 q0 = p[0], q1 = p[1], q2 = p[2];
        av[0] = q0.x; av[1] = q0.y; av[2] = q0.z; av[3] = q0.w;
        av[4] = q1.x; av[5] = q1.y; av[6] = q1.z; av[7] = q1.w;
        av[8] = q2.x; av[9] = q2.y; av[10] = q2.z; av[11] = q2.w;
    }
#pragma unroll
    for (int j = 0; j < 12; ++j) agg[j] = 0.f;

    int p0 = row_start[node], p1 = row_start[node + 1];
    int np = p1 - p0;
    float denom = 0.f;

    const unsigned char*  fs8l  = (const unsigned char*)fs + d0;   // fp8: d0 bytes
    const unsigned short* fs16l = (const unsigned short*)fs + d0;  // bf16
    const int* ip = csr_src + p0;

    float fvA[12], fvB[12];
    if (np > 0) LOADFV(ip[0], fvA);
    if (np > 1) LOADFV(ip[1], fvB);

    int i = 0;
    for (; i + 2 <= np; i += 2) {
        PROCESS(fvA);
        if (i + 2 < np) LOADFV(ip[i + 2], fvA);
        PROCESS(fvB);
        if (i + 3 < np) LOADFV(ip[i + 3], fvB);
    }
    if (i < np) PROCESS(fvA);

    float inv = (denom > 0.f) ? 1.0f / denom : 0.f;
    float vals[12];
#pragma unroll
    for (int j = 0; j < 12; ++j) {
        float v = agg[j] * inv;
        vals[j] = (v > 0.f) ? v : (__expf(v) - 1.0f);
    }
    if (resid != nullptr) {
        float rv[12];
        load12(resid + (size_t)node * DIM + d0, rv);
#pragma unroll
        for (int j = 0; j < 12; ++j) vals[j] += rv[j];
    }
    float s1 = 0.f;
#pragma unroll
    for (int j = 0; j < 12; ++j) s1 += vals[j];
    s1 = group_sum<64>(s1);
    float mu = s1 * (1.0f / DIM);
    float s2 = 0.f;
#pragma unroll
    for (int j = 0; j < 12; ++j) {
        float dlt = vals[j] - mu;
        s2 = fmaf(dlt, dlt, s2);
    }
    s2 = group_sum<64>(s2);
    float rs = rsqrtf(s2 * (1.0f / DIM) + 1e-5f);

    float wv[12], bv[12];
    {
        const float4* p = reinterpret_cast<const float4*>(ln_w + d0);
        float4 q0 = p[0], q1 = p[1], q2 = p[2];
        wv[0] = q0.x; wv[1] = q0.y; wv[2] = q0.z; wv[3] = q0.w;
        wv[4] = q1.x; wv[5] = q1.y; wv[6] = q1.z; wv[7] = q1.w;
        wv[8] = q2.x; wv[9] = q2.y; wv[10] = q2.z; wv[11] = q2.w;
        const float4* pb = reinterpret_cast<const float4*>(ln_b + d0);
        float4 r0 = pb[0], r1 = pb[1], r2 = pb[2];
        bv[0] = r0.x; bv[1] = r0.y; bv[2] = r0.z; bv[3] = r0.w;
        bv[4] = r1.x; bv[5] = r1.y; bv[6] = r1.z; bv[7] = r1.w;
        bv[8] = r2.x; bv[9] = r2.y; bv[10] = r2.z; bv[11] = r2.w;
    }
    float o[12];
#pragma unroll
    for (int j = 0; j < 12; ++j)
        o[j] = (vals[j] - mu) * rs * wv[j] + bv[j];

    if (outf != nullptr) {
        float* op = outf + (size_t)node * DIM + d0;
#pragma unroll
        for (int qq = 0; qq < 3; ++qq) {
            float4 t4 = make_float4(o[qq * 4 + 0], o[qq * 4 + 1], o[qq * 4 + 2], o[qq * 4 + 3]);
            *reinterpret_cast<float4*>(op + qq * 4) = t4;
        }
    }
    if (outb != nullptr) {
        __hip_bfloat16 hb[12];
#pragma unroll
        for (int j = 0; j < 12; ++j) hb[j] = __float2bfloat16(o[j]);
        unsigned short* op = (unsigned short*)outb + (size_t)node * DIM + d0;
#pragma unroll
        for (int qq = 0; qq < 3; ++qq)
            *reinterpret_cast<ushort4*>(op + qq * 4) =
                *reinterpret_cast<ushort4*>(&hb[qq * 4]);
    }
}

// ---------------------------------------------------------------------------
// Dual bf16 MFMA GEMM: BM=256 x BN=128, BK=64, 512 threads (8 waves, 4x2).
// C1F8: C1 (=fs) written as fp8 e4m3; C2 (=fd) always bf16.
// ---------------------------------------------------------------------------
template <bool C1F8>
__global__ __launch_bounds__(512) void gemm_mfma_dual_kernel(
    const bf16_t* __restrict__ Xb,   // [M][768]
    const bf16_t* __restrict__ Wt,   // [1536][768]
    const float* __restrict__ b1, const float* __restrict__ b2,
    void* __restrict__ C1, __hip_bfloat16* __restrict__ C2, int M) {
    __shared__ __align__(16) bf16_t As[256 * 64];   // 32 KB
    __shared__ __align__(16) bf16_t Bs[128 * 64];   // 16 KB

    const int nwg = gridDim.x;
    const int o = blockIdx.x;
    const int q = nwg >> 3, r = nwg & 7;
    const int xcd = o & 7, jj = o >> 3;
    const int lin = (xcd < r ? xcd * (q + 1) : r * (q + 1) + (xcd - r) * q) + jj;
    const int bn = (lin % 12) * 128;
    const int bm = (lin / 12) * 256;

    const int tid = threadIdx.x;
    const int lane = tid & 63;
    const int w = tid >> 6;         // 0..7
    const int wrow = w >> 1;        // 0..3
    const int wcol = w & 1;         // 0..1

    f32x4 acc[4][4];
    {
        const float* bp = (bn < DIM) ? b1 : b2;
        int cb = (bn < DIM) ? bn : bn - DIM;
#pragma unroll
        for (int ni = 0; ni < 4; ++ni) {
            float bv = bp[cb + wcol * 64 + ni * 16 + (lane & 15)];
#pragma unroll
            for (int mi = 0; mi < 4; ++mi) acc[mi][ni] = f32x4{bv, bv, bv, bv};
        }
    }

    const int trow = tid >> 3;
    const int tcol = (tid & 7) * 8;

    for (int k0 = 0; k0 < DIM; k0 += 64) {
#pragma unroll
        for (int p = 0; p < 4; ++p) {
            int rr = p * 64 + trow;
            int col = tcol ^ ((rr & 7) << 3);
            int rg = bm + rr; rg = rg < M ? rg : M - 1;
            GLOAD_LDS16(Xb + (size_t)rg * DIM + k0 + col, &As[(p * 64 + w * 8) * 64]);
        }
#pragma unroll
        for (int p = 0; p < 2; ++p) {
            int rr = p * 64 + trow;
            int col = tcol ^ ((rr & 7) << 3);
            GLOAD_LDS16(Wt + (size_t)(bn + rr) * DIM + k0 + col, &Bs[(p * 64 + w * 8) * 64]);
        }
        __syncthreads();

#pragma unroll
        for (int kk = 0; kk < 2; ++kk) {
            bf16x8 af[4], bfr[4];
            int ke = kk * 32 + (lane >> 4) * 8;
#pragma unroll
            for (int mi = 0; mi < 4; ++mi) {
                int rr = wrow * 64 + mi * 16 + (lane & 15);
                af[mi] = *(const bf16x8*)&As[rr * 64 + (ke ^ ((rr & 7) << 3))];
            }
#pragma unroll
            for (int ni = 0; ni < 4; ++ni) {
                int rr = wcol * 64 + ni * 16 + (lane & 15);
                bfr[ni] = *(const bf16x8*)&Bs[rr * 64 + (ke ^ ((rr & 7) << 3))];
            }
#pragma unroll
            for (int mi = 0; mi < 4; ++mi)
#pragma unroll
                for (int ni = 0; ni < 4; ++ni)
                    acc[mi][ni] = __builtin_amdgcn_mfma_f32_16x16x32_bf16(
                        af[mi], bfr[ni], acc[mi][ni], 0, 0, 0);
        }
        __syncthreads();
    }

    if (bn < DIM) {
        int cb = bn;
#pragma unroll
        for (int mi = 0; mi < 4; ++mi) {
#pragma unroll
            for (int j = 0; j < 4; ++j) {
                int row = bm + wrow * 64 + mi * 16 + (lane >> 4) * 4 + j;
                if (row < M) {
#pragma unroll
                    for (int ni = 0; ni < 4; ++ni) {
                        int col = cb + wcol * 64 + ni * 16 + (lane & 15);
                        if constexpr (C1F8) {
                            ((unsigned char*)C1)[(size_t)row * DIM + col] =
                                f32_to_fp8(acc[mi][ni][j]);
                        } else {
                            ((__hip_bfloat16*)C1)[(size_t)row * DIM + col] =
                                __float2bfloat16(acc[mi][ni][j]);
                        }
                    }
                }
            }
        }
    } else {
        int cb = bn - DIM;
#pragma unroll
        for (int mi = 0; mi < 4; ++mi) {
#pragma unroll
            for (int j = 0; j < 4; ++j) {
                int row = bm + wrow * 64 + mi * 16 + (lane >> 4) * 4 + j;
                if (row < M) {
#pragma unroll
                    for (int ni = 0; ni < 4; ++ni) {
                        int col = cb + wcol * 64 + ni * 16 + (lane & 15);
                        C2[(size_t)row * DIM + col] = __float2bfloat16(acc[mi][ni][j]);
                    }
                }
            }
        }
    }
}

// ---------------------------------------------------------------------------
extern "C" void kernel_launch(void* const* d_in, const int* in_sizes, int n_in,
                              void* d_out, int out_size, void* d_ws, size_t ws_size,
                              hipStream_t stream) {
    const float* x     = (const float*)d_in[0];
    const int*   src   = (const int*)d_in[1];
    const int*   dst   = (const int*)d_in[2];
    const float* W1s   = (const float*)d_in[3];
    const float* b1s   = (const float*)d_in[4];
    const float* W1d   = (const float*)d_in[5];
    const float* b1d   = (const float*)d_in[6];
    const float* attn1 = (const float*)d_in[7];
    const float* ln1w  = (const float*)d_in[8];
    const float* ln1b  = (const float*)d_in[9];
    const float* Wos   = (const float*)d_in[10];
    const float* bos   = (const float*)d_in[11];
    const float* Wod   = (const float*)d_in[12];
    const float* bod   = (const float*)d_in[13];
    const float* attno = (const float*)d_in[14];
    const float* lnow  = (const float*)d_in[15];
    const float* lnob  = (const float*)d_in[16];
    float* out = (float*)d_out;

    const int N = in_sizes[0] / DIM;   // 20000
    const int E = in_sizes[1];         // 320000

    __hip_bfloat16* fsb = (__hip_bfloat16*)d_ws;   // bf16 region (layer2) / fp8 uses half
    __hip_bfloat16* fdb = fsb + (size_t)N * DIM;
    __hip_bfloat16* Xb  = fdb + (size_t)N * DIM;
    __hip_bfloat16* W1t = Xb + (size_t)N * DIM;   // 4 contiguous 768x768 mats
    __hip_bfloat16* Wot = W1t + (size_t)2 * DIM * DIM;
    int* csr_src   = (int*)(Wot + (size_t)2 * DIM * DIM);
    int* row_start = csr_src + E;
    int* cursor    = row_start + (N + 1);
    int* deg       = cursor + N;
    int* excl      = deg + N;
    int* bsum      = excl + N;

    const int nb = (N + 255) / 256;

    // --- CSR by dst (shared by both layers): hist -> 3-stage scan -> scatter
    hipMemsetAsync(deg, 0, (size_t)N * sizeof(int), stream);
    hist_kernel<<<(E + 255) / 256, 256, 0, stream>>>(dst, deg, E);
    scan_block_kernel<<<nb, 256, 0, stream>>>(deg, excl, bsum, N);
    scan_tops_kernel<<<1, 1024, 0, stream>>>(bsum, nb);
    scan_fix_kernel<<<nb, 256, 0, stream>>>(excl, bsum, row_start, cursor, N, E);
    scatter_kernel<<<(E + 255) / 256, 256, 0, stream>>>(src, dst, cursor, csr_src, E);

    // --- weight transposes, all 4 in one dispatch
    dim3 tg(DIM / 32, DIM / 32, 4);
    transpose4_bf16_kernel<<<tg, 256, 0, stream>>>(W1s, W1d, Wos, Wod, W1t);

    const int n8 = N * DIM / 8;
    const int mt = (N + 255) / 256;
    const int nwg = mt * 12;  // 1D swizzled grid (256x128 tiles)

    // --- layer 1: GEMM (fs -> fp8) -> gat<8, fp8> (bf16 resid from Xb; h -> Xb)
    conv_bf16_kernel<<<(n8 + 255) / 256, 256, 0, stream>>>(x, Xb, n8);
    gemm_mfma_dual_kernel<true><<<nwg, 512, 0, stream>>>(
        (const bf16_t*)Xb, (const bf16_t*)W1t, b1s, b1d, (void*)fsb, fdb, N);
    gat_node_kernel<8, true><<<(N + 3) / 4, 256, 0, stream>>>(
        (const void*)fsb, (const unsigned short*)fdb, row_start, csr_src,
        attn1, (const unsigned short*)Xb, ln1w, ln1b, nullptr, Xb, N);

    // --- layer 2: GEMM (bf16) -> gat<1, bf16> -> final f32 out
    gemm_mfma_dual_kernel<false><<<nwg, 512, 0, stream>>>(
        (const bf16_t*)Xb, (const bf16_t*)Wot, bos, bod, (void*)fsb, fdb, N);
    gat_node_kernel<1, false><<<(N + 3) / 4, 256, 0, stream>>>(
        (const void*)fsb, (const unsigned short*)fdb, row_start, csr_src,
        attno, nullptr, lnow, lnob, out, nullptr, N);
}